// Round 10
// baseline (2358.993 us; speedup 1.0000x reference)
//
#include <hip/hip_runtime.h>
#include <hip/hip_bf16.h>
#include <math.h>

// ---------------- problem constants ----------------
#define B_   128
#define S_   50
#define BS_  (B_*S_)        // 6400
#define E_   512
#define D_   1024
#define H_   16
#define DK_  64
#define L_   4
#define FF_  4096
#define V_   100000

typedef short bf8_t __attribute__((ext_vector_type(8)));
typedef float f32x4 __attribute__((ext_vector_type(4)));
typedef unsigned short u16;

__device__ __forceinline__ float gelu_exact(float x) {
    return 0.5f * x * (1.0f + erff(x * 0.70710678118654752440f));
}
__device__ __forceinline__ u16 f2bf(float f) {
    unsigned int u = __float_as_uint(f);
    return (u16)((u + 0x7FFFu + ((u >> 16) & 1u)) >> 16);
}
__device__ __forceinline__ float bf2f(u16 u) {
    return __uint_as_float(((unsigned int)u) << 16);
}

// async global->LDS, 16B per lane (dest wave-uniform base + lane*16)
__device__ __forceinline__ void gload16(const u16* g, u16* l) {
    auto* g1 = reinterpret_cast<const __attribute__((address_space(1))) unsigned int*>(
                   reinterpret_cast<uintptr_t>(g));
    auto* l3 = reinterpret_cast<__attribute__((address_space(3))) unsigned int*>(
                   reinterpret_cast<uintptr_t>(l));
    __builtin_amdgcn_global_load_lds(g1, l3, 16, 0, 0);
}

// ---------------- weight transpose bodies ----------------
__device__ __forceinline__ void wtrans_body(
    const float* __restrict__ W, u16* __restrict__ Wt,
    int K, int N, int nb, int kb, int dstRowOff)
{
    __shared__ float t[32][33];
    int c = threadIdx.x & 31, r0 = threadIdx.x >> 5;
    #pragma unroll
    for (int rr = 0; rr < 32; rr += 8)
        t[rr + r0][c] = W[(size_t)(kb + rr + r0) * N + nb + c];
    __syncthreads();
    #pragma unroll
    for (int rr = 0; rr < 32; rr += 8)
        Wt[(size_t)(dstRowOff + nb + rr + r0) * K + kb + c] = f2bf(t[c][rr + r0]);
}

__global__ __launch_bounds__(256) void wtrans(
    const float* __restrict__ W, u16* __restrict__ Wt,
    int K, int N, long srcLS, long dstLS, int dstRowOff)
{
    int l = blockIdx.z;
    wtrans_body(W + (size_t)l * srcLS, Wt + (size_t)l * dstLS,
                K, N, blockIdx.x * 32, blockIdx.y * 32, dstRowOff);
}

__global__ __launch_bounds__(256) void wtrans_qkv(
    const float* __restrict__ wq, const float* __restrict__ wk, const float* __restrict__ wv,
    u16* __restrict__ dst)
{
    int z = blockIdx.z;
    int l = z & 3, which = z >> 2;
    const float* W = (which == 0 ? wq : which == 1 ? wk : wv) + (size_t)l * (D_ * D_);
    u16* Wt = dst + (size_t)l * (3 * D_ * D_) + (size_t)which * (D_ * D_);
    wtrans_body(W, Wt, D_, D_, blockIdx.x * 32, blockIdx.y * 32, 0);
}

struct WT8 { const float* s[8]; u16* d[8]; };
__global__ __launch_bounds__(256) void wtrans8(WT8 p)
{
    int z = blockIdx.z;
    wtrans_body(p.s[z], p.d[z], D_, D_, blockIdx.x * 32, blockIdx.y * 32, 0);
}

__global__ __launch_bounds__(256) void wtrans_ff(
    const float* __restrict__ w1, const float* __restrict__ w2,
    u16* __restrict__ d1, u16* __restrict__ d2)
{
    if (blockIdx.z == 0)
        wtrans_body(w1, d1, D_, FF_, blockIdx.x * 32, blockIdx.y * 32, 0);
    else
        wtrans_body(w2, d2, FF_, D_, blockIdx.y * 32, blockIdx.x * 32, 0);
}

// ---------------- embedding gather + concat (bf16 out) ----------------
__global__ __launch_bounds__(256) void embed_concat(
    const float* __restrict__ mt, const float* __restrict__ ft, const float* __restrict__ et,
    const int* __restrict__ mids, const int* __restrict__ fids, const int* __restrict__ eids,
    u16* __restrict__ xinb)
{
    int bs = blockIdx.x;
    int mid = mids[bs], fid = fids[bs], eid = eids[bs];
    const float* srcs[3] = { mt + (size_t)mid * E_, ft + (size_t)fid * E_, et + (size_t)eid * E_ };
    u16* dst = xinb + (size_t)bs * (3 * E_);
    for (int i = threadIdx.x; i < 384; i += 256) {
        int seg = i >> 7, off = i & 127;
        float4 v = reinterpret_cast<const float4*>(srcs[seg])[off];
        ushort4 b;
        b.x = f2bf(v.x); b.y = f2bf(v.y); b.z = f2bf(v.z); b.w = f2bf(v.w);
        reinterpret_cast<ushort4*>(dst + seg * E_)[off] = b;
    }
}

// ---------------- setup misc ----------------
__global__ __launch_bounds__(256) void setup_misc(
    const float* __restrict__ bq, const float* __restrict__ bk, const float* __restrict__ bv,
    const float* __restrict__ cb1, const float* __restrict__ nb1,
    const float* __restrict__ mkb, const float* __restrict__ mvb,
    float* __restrict__ bqkv, float* __restrict__ bcn, float* __restrict__ bkv,
    float* __restrict__ pet)
{
    int bi = blockIdx.x, tid = threadIdx.x;
    if (bi < 4) {
        for (int c = tid; c < 3072; c += 256) {
            float v = (c < 1024) ? bq[bi * 1024 + c]
                    : (c < 2048) ? bk[bi * 1024 + c - 1024]
                                 : bv[bi * 1024 + c - 2048];
            bqkv[bi * 3072 + c] = v;
        }
    } else if (bi == 4) {
        for (int c = tid; c < 2048; c += 256)
            bcn[c] = (c < 1024) ? cb1[c] : nb1[c - 1024];
    } else if (bi == 5) {
        for (int c = tid; c < 2048; c += 256)
            bkv[c] = (c < 1024) ? mkb[c] : mvb[c - 1024];
    } else {
        int s = bi - 6;
        const float cc = -logf(10000.0f) / 512.0f;
        for (int d = tid; d < D_; d += 256) {
            int second = d >= 512;
            int c2 = second ? d - 512 : d;
            int i = c2 >> 1;
            float div = expf(cc * (float)(2 * i));
            float aa = (float)s * div * (second ? 1.5f : 1.0f);
            pet[s * D_ + d] = (c2 & 1) ? cosf(aa) : sinf(aa);
        }
    }
}

// ---------------- 256x256 / BK=64 / 8-wave, 4-phase counted-vmcnt pipeline ----------------
// A bf16 [M,lda], Wt bf16 [N,K] row-major, bias fp32[N].
// M%256==0, N%256==0, K%64==0, nk>=2. grid (N/256, M/256). 512 thr = 8 waves (2M x 4N).
// LDS per operand: 2 dbuf x [2 kh][256 rows][32], chunk swizzle p^((row>>1)&3).
// Per K-tile: 4 phases (mg x kh); each stages ONE half-tile of tile t+1;
// vmcnt(4) at phases 0/2 (2 half-tiles stay in flight) — never 0 in steady state.
__global__ __launch_bounds__(512, 1) void gemm256(
    const u16* __restrict__ A, int lda, const u16* __restrict__ Wt,
    const float* __restrict__ bias,
    u16* __restrict__ Cb, int ldcb,
    int N, int K, int act, const float* __restrict__ pe)
{
    __shared__ u16 As[2 * 16384];   // 2 buf x (2 kh x 8192)
    __shared__ u16 Bs[2 * 16384];
    const int tid  = threadIdx.x;
    const int lane = tid & 63;
    const int wid  = tid >> 6;          // 0..7
    const int wr   = wid >> 2;          // 0..1 (M)
    const int wc   = wid & 3;           // 0..3 (N)

    // XCD-bijective swizzle (m204)
    const int gx  = gridDim.x;
    const int nwg = gx * gridDim.y;
    int orig = blockIdx.y * gx + blockIdx.x;
    int qq = nwg >> 3, rr2 = nwg & 7, xcd = orig & 7, idx = orig >> 3;
    int wgid = (xcd < rr2) ? (xcd * (qq + 1) + idx)
                           : (rr2 * (qq + 1) + (xcd - rr2) * qq + idx);
    const int rowBase = (wgid / gx) * 256;
    const int colBase = (wgid % gx) * 256;

    const int fr = lane & 15;
    const int hi = lane >> 4;

    // ---- staging geometry: per half-tile, 2 gloads/thread; slot = row*4 + p ----
    const int slot0 = wid * 64 + lane;
    const int slot1 = slot0 + 512;
    const int r0s = slot0 >> 2, p0s = slot0 & 3;
    const int r1s = slot1 >> 2, p1s = slot1 & 3;
    const u16* aSrc0 = A  + (size_t)(rowBase + r0s) * lda + ((p0s ^ ((r0s >> 1) & 3)) << 3);
    const u16* aSrc1 = A  + (size_t)(rowBase + r1s) * lda + ((p1s ^ ((r1s >> 1) & 3)) << 3);
    const u16* bSrc0 = Wt + (size_t)(colBase + r0s) * K   + ((p0s ^ ((r0s >> 1) & 3)) << 3);
    const u16* bSrc1 = Wt + (size_t)(colBase + r1s) * K   + ((p1s ^ ((r1s >> 1) & 3)) << 3);
    const int dOff0 = slot0 * 8;        // u16 units; = lane*16B within wave group
    const int dOff1 = slot1 * 8;

    // ---- fragment read constants ----
    const int key  = (fr >> 1) & 3;
    const int aRdC = (wr * 128 + fr) * 32 + ((hi ^ key) << 3);   // + mg*2048 + mi*512 + kh*8192
    const int bRdC = (wc * 64  + fr) * 32 + ((hi ^ key) << 3);   // + n*512 + kh*8192

    f32x4 acc[8][4] = {};
    const int nk = K >> 6;

    u16* Acur = As;          u16* Bcur = Bs;
    u16* Anxt = As + 16384;  u16* Bnxt = Bs + 16384;

    // prologue: stage tile 0 (order A0, B0, A1, B1 — vmcnt counting relies on it)
    gload16(aSrc0, Acur + dOff0);          gload16(aSrc1, Acur + dOff1);
    __builtin_amdgcn_sched_barrier(0);
    gload16(bSrc0, Bcur + dOff0);          gload16(bSrc1, Bcur + dOff1);
    __builtin_amdgcn_sched_barrier(0);
    gload16(aSrc0 + 32, Acur + 8192 + dOff0); gload16(aSrc1 + 32, Acur + 8192 + dOff1);
    __builtin_amdgcn_sched_barrier(0);
    gload16(bSrc0 + 32, Bcur + 8192 + dOff0); gload16(bSrc1 + 32, Bcur + 8192 + dOff1);
    __builtin_amdgcn_sched_barrier(0);

    for (int t = 0; t < nk; ++t) {
        const bool st = (t + 1 < nk);
        const int kb1 = (t + 1) << 6;
        bf8_t bfr[4], afr[4];

        // ---- phase 0: (mg=0, kh=0); gate A0,B0 of cur; stage A-kh0 of t+1 ----
        asm volatile("s_waitcnt vmcnt(4)" ::: "memory");
        __builtin_amdgcn_s_barrier();
        __builtin_amdgcn_sched_barrier(0);
        #pragma unroll
        for (int n = 0; n < 4; ++n)
            bfr[n] = *reinterpret_cast<const bf8_t*>(&Bcur[n * 512 + bRdC]);
        #pragma unroll
        for (int m = 0; m < 4; ++m)
            afr[m] = *reinterpret_cast<const bf8_t*>(&Acur[m * 512 + aRdC]);
        if (st) { gload16(aSrc0 + kb1, Anxt + dOff0); gload16(aSrc1 + kb1, Anxt + dOff1); }
        __builtin_amdgcn_sched_barrier(0);
        __builtin_amdgcn_s_setprio(1);
        #pragma unroll
        for (int m = 0; m < 4; ++m)
            #pragma unroll
            for (int n = 0; n < 4; ++n)
                acc[m][n] = __builtin_amdgcn_mfma_f32_16x16x32_bf16(afr[m], bfr[n], acc[m][n], 0, 0, 0);
        __builtin_amdgcn_s_setprio(0);
        __builtin_amdgcn_s_barrier();
        __builtin_amdgcn_sched_barrier(0);

        // ---- phase 1: (mg=1, kh=0); reuse bfr; stage B-kh0 of t+1 ----
        #pragma unroll
        for (int m = 0; m < 4; ++m)
            afr[m] = *reinterpret_cast<const bf8_t*>(&Acur[2048 + m * 512 + aRdC]);
        if (st) { gload16(bSrc0 + kb1, Bnxt + dOff0); gload16(bSrc1 + kb1, Bnxt + dOff1); }
        __builtin_amdgcn_sched_barrier(0);
        __builtin_amdgcn_s_setprio(1);
        #pragma unroll
        for (int m = 0; m < 4; ++m)
            #pragma unroll
            for (int n = 0; n < 4; ++n)
                acc[4 + m][n] = __builtin_amdgcn_mfma_f32_16x16x32_bf16(afr[m], bfr[n], acc[4 + m][n], 0, 0, 0);
        __builtin_amdgcn_s_setprio(0);

        // ---- phase 2: (mg=0, kh=1); gate A1,B1 of cur; stage A-kh1 of t+1 ----
        if (st) asm volatile("s_waitcnt vmcnt(4)" ::: "memory");
        else    asm volatile("s_waitcnt vmcnt(0)" ::: "memory");
        __builtin_amdgcn_s_barrier();
        __builtin_amdgcn_sched_barrier(0);
        #pragma unroll
        for (int n = 0; n < 4; ++n)
            bfr[n] = *reinterpret_cast<const bf8_t*>(&Bcur[8192 + n * 512 + bRdC]);
        #pragma unroll
        for (int m = 0; m < 4; ++m)
            afr[m] = *reinterpret_cast<const bf8_t*>(&Acur[8192 + m * 512 + aRdC]);
        if (st) { gload16(aSrc0 + kb1 + 32, Anxt + 8192 + dOff0); gload16(aSrc1 + kb1 + 32, Anxt + 8192 + dOff1); }
        __builtin_amdgcn_sched_barrier(0);
        __builtin_amdgcn_s_setprio(1);
        #pragma unroll
        for (int m = 0; m < 4; ++m)
            #pragma unroll
            for (int n = 0; n < 4; ++n)
                acc[m][n] = __builtin_amdgcn_mfma_f32_16x16x32_bf16(afr[m], bfr[n], acc[m][n], 0, 0, 0);
        __builtin_amdgcn_s_setprio(0);
        __builtin_amdgcn_s_barrier();
        __builtin_amdgcn_sched_barrier(0);

        // ---- phase 3: (mg=1, kh=1); reuse bfr; stage B-kh1 of t+1 ----
        #pragma unroll
        for (int m = 0; m < 4; ++m)
            afr[m] = *reinterpret_cast<const bf8_t*>(&Acur[8192 + 2048 + m * 512 + aRdC]);
        if (st) { gload16(bSrc0 + kb1 + 32, Bnxt + 8192 + dOff0); gload16(bSrc1 + kb1 + 32, Bnxt + 8192 + dOff1); }
        __builtin_amdgcn_sched_barrier(0);
        __builtin_amdgcn_s_setprio(1);
        #pragma unroll
        for (int m = 0; m < 4; ++m)
            #pragma unroll
            for (int n = 0; n < 4; ++n)
                acc[4 + m][n] = __builtin_amdgcn_mfma_f32_16x16x32_bf16(afr[m], bfr[n], acc[4 + m][n], 0, 0, 0);
        __builtin_amdgcn_s_setprio(0);
        // next tile's phase-0 entry provides the vmcnt+barrier

        u16* tp;
        tp = Acur; Acur = Anxt; Anxt = tp;
        tp = Bcur; Bcur = Bnxt; Bnxt = tp;
    }

    // ---- epilogue: C/D map col=lane&15, row=(lane>>4)*4+reg ----
    #pragma unroll
    for (int m = 0; m < 8; ++m) {
        int r0 = rowBase + wr * 128 + m * 16 + hi * 4;
        #pragma unroll
        for (int n = 0; n < 4; ++n) {
            int c = colBase + wc * 64 + n * 16 + fr;
            float bv = bias ? bias[c] : 0.0f;
            #pragma unroll
            for (int r = 0; r < 4; ++r) {
                float v = acc[m][n][r] + bv;
                if (act == 1) v = gelu_exact(v);
                if (pe) v += pe[(size_t)((r0 + r) % S_) * 1024 + c];
                Cb[(size_t)(r0 + r) * ldcb + c] = f2bf(v);
            }
        }
    }
}

// ---------------- small bf16 GEMM (M=128 heads), BM=64, depth-2 counted vmcnt ----------------
template<int BM>
__global__ __launch_bounds__(256) void gemm_bf16_t(
    const u16* __restrict__ A, int lda, const u16* __restrict__ Wt,
    const float* __restrict__ bias, float* __restrict__ Cf,
    u16* __restrict__ Cb, int ldcb, u16* __restrict__ Cb2, int ldcb2,
    int N, int K, int act)
{
    constexpr int MR   = BM / 32;
    constexpr int AL   = BM / 64;
    constexpr int ABUF = BM * 32;
    __shared__ u16 As[2 * ABUF];
    __shared__ u16 Bs[2 * 4096];
    const int tid  = threadIdx.x;
    const int lane = tid & 63;
    const int wid  = tid >> 6;
    const int wr   = wid >> 1, wc = wid & 1;

    const int rowBase = blockIdx.y * BM;
    const int colBase = blockIdx.x * 128;

    const int fr = lane & 15;
    const int hi = lane >> 4;

    const int sRowL  = lane >> 2;
    const int sChunk = lane & 3;
    const int aRow0 = wid * (BM / 4) + sRowL;
    const int aKey  = (aRow0 >> 1) & 3;
    const u16* aS0 = A + (size_t)(rowBase + aRow0) * lda + ((sChunk ^ aKey) << 3);
    const u16* aS1 = aS0 + (size_t)16 * lda;
    const int ldsA0 = (wid * (BM / 4)) * 32;
    const int ldsA1 = ldsA0 + 512;
    const int bRow0 = wid * 32 + sRowL;
    const int bKey  = (bRow0 >> 1) & 3;
    const u16* bS0 = Wt + (size_t)(colBase + bRow0) * K + ((sChunk ^ bKey) << 3);
    const u16* bS1 = bS0 + (size_t)16 * K;
    const int ldsB0 = (wid * 32) * 32;
    const int ldsB1 = ldsB0 + 512;

    const int swz = ((hi ^ ((fr >> 1) & 3)) << 3);
    const int aRd = (wr * (BM / 2) + fr) * 32 + swz;
    const int bRd = (wc * 64 + fr) * 32 + swz;

    f32x4 acc[MR][4] = {};
    const int nk = K >> 5;

    auto STAGE = [&](int kb, int buf) {
        u16* dA = As + buf * ABUF;
        u16* dB = Bs + buf * 4096;
        gload16(aS0 + kb, dA + ldsA0);
        if constexpr (AL == 2) gload16(aS1 + kb, dA + ldsA1);
        gload16(bS0 + kb, dB + ldsB0);
        gload16(bS1 + kb, dB + ldsB1);
    };

    STAGE(0, 0);
    __builtin_amdgcn_sched_barrier(0);
    STAGE(32, 1);
    __builtin_amdgcn_sched_barrier(0);
    if constexpr (BM == 128) asm volatile("s_waitcnt vmcnt(4)\n\ts_barrier" ::: "memory");
    else                     asm volatile("s_waitcnt vmcnt(3)\n\ts_barrier" ::: "memory");
    __builtin_amdgcn_sched_barrier(0);

    for (int t = 0; t < nk; ++t) {
        const int cur = t & 1;
        const u16* bA = As + cur * ABUF;
        const u16* bB = Bs + cur * 4096;
        bf8_t af[MR], bf[4];
        #pragma unroll
        for (int m = 0; m < MR; ++m)
            af[m] = *reinterpret_cast<const bf8_t*>(&bA[aRd + m * 512]);
        #pragma unroll
        for (int n = 0; n < 4; ++n)
            bf[n] = *reinterpret_cast<const bf8_t*>(&bB[bRd + n * 512]);
        #pragma unroll
        for (int m = 0; m < MR; ++m)
            #pragma unroll
            for (int n = 0; n < 4; ++n)
                acc[m][n] = __builtin_amdgcn_mfma_f32_16x16x32_bf16(af[m], bf[n], acc[m][n], 0, 0, 0);
        if (t == nk - 1) break;
        __builtin_amdgcn_sched_barrier(0);
        asm volatile("s_waitcnt lgkmcnt(0)\n\ts_barrier" ::: "memory");
        __builtin_amdgcn_sched_barrier(0);
        if (t + 2 < nk) {
            STAGE((t + 2) << 5, cur);
            __builtin_amdgcn_sched_barrier(0);
            if constexpr (BM == 128) asm volatile("s_waitcnt vmcnt(4)\n\ts_barrier" ::: "memory");
            else                     asm volatile("s_waitcnt vmcnt(3)\n\ts_barrier" ::: "memory");
        } else {
            asm volatile("s_waitcnt vmcnt(0)\n\ts_barrier" ::: "memory");
        }
        __builtin_amdgcn_sched_barrier(0);
    }

    const int orow = hi << 2;
    #pragma unroll
    for (int m = 0; m < MR; ++m) {
        int r0 = rowBase + wr * (BM / 2) + m * 16 + orow;
        #pragma unroll
        for (int n = 0; n < 4; ++n) {
            int c = colBase + wc * 64 + n * 16 + fr;
            float bv = bias ? bias[c] : 0.0f;
            #pragma unroll
            for (int r = 0; r < 4; ++r) {
                float v = acc[m][n][r] + bv;
                if (act == 1) v = gelu_exact(v);
                if (Cf)  Cf [(size_t)(r0 + r) * N + c] = v;
                if (Cb)  Cb [(size_t)(r0 + r) * ldcb  + c] = f2bf(v);
                if (Cb2) Cb2[(size_t)(r0 + r) * ldcb2 + c] = f2bf(v);
            }
        }
    }
}

// ---------------- logits GEMM: fp32 W streamed, reg-staged pipeline ----------------
__global__ __launch_bounds__(256) void gemm_logits(
    const float* __restrict__ A, int lda, const float* __restrict__ W,
    const float* __restrict__ bias, float* __restrict__ C, int N, int K)
{
    __shared__ u16 As[2][128][40];
    __shared__ u16 Bs[2][128][40];
    const int tid  = threadIdx.x;
    const int lane = tid & 63;
    const int wid  = tid >> 6;
    const int wr   = wid >> 1, wc = wid & 1;
    const int colBase = blockIdx.x * 128;

    const int a_r = tid >> 1;
    const int a_h = (tid & 1) << 4;
    const int b_c = tid & 127;
    const int b_h = (tid >> 7) << 4;

    const int fr = lane & 15;
    const int fk = (lane >> 4) << 3;

    f32x4 acc[4][4] = {};
    const int nvalid = N - colBase;
    const bool valid = b_c < nvalid;
    const int nk = K >> 5;

    float4 aR[4];
    float  bR[16];

    auto LD = [&](int kb) {
        const float* Ap = A + (size_t)a_r * lda + kb + a_h;
        #pragma unroll
        for (int q = 0; q < 4; ++q)
            aR[q] = *reinterpret_cast<const float4*>(Ap + q * 4);
        const float* Wp = W + (size_t)(kb + b_h) * N + colBase + b_c;
        #pragma unroll
        for (int kk = 0; kk < 16; ++kk)
            bR[kk] = valid ? Wp[(size_t)kk * N] : 0.0f;
    };
    auto ST = [&](int buf) {
        #pragma unroll
        for (int q = 0; q < 4; ++q) {
            ushort4 bb;
            bb.x = f2bf(aR[q].x); bb.y = f2bf(aR[q].y);
            bb.z = f2bf(aR[q].z); bb.w = f2bf(aR[q].w);
            *reinterpret_cast<ushort4*>(&As[buf][a_r][a_h + q * 4]) = bb;
        }
        u16 tmp[16];
        #pragma unroll
        for (int kk = 0; kk < 16; ++kk) tmp[kk] = f2bf(bR[kk]);
        *reinterpret_cast<bf8_t*>(&Bs[buf][b_c][b_h])     = *reinterpret_cast<const bf8_t*>(tmp);
        *reinterpret_cast<bf8_t*>(&Bs[buf][b_c][b_h + 8]) = *reinterpret_cast<const bf8_t*>(tmp + 8);
    };

    LD(0); ST(0);
    __syncthreads();

    for (int t = 0; t < nk; ++t) {
        if (t + 1 < nk) LD((t + 1) << 5);
        const int cur = t & 1;
        bf8_t af[4], bfv[4];
        #pragma unroll
        for (int m = 0; m < 4; ++m)
            af[m] = *reinterpret_cast<const bf8_t*>(&As[cur][wr * 64 + m * 16 + fr][fk]);
        #pragma unroll
        for (int n = 0; n < 4; ++n)
            bfv[n] = *reinterpret_cast<const bf8_t*>(&Bs[cur][wc * 64 + n * 16 + fr][fk]);
        #pragma unroll
        for (int m = 0; m < 4; ++m)
            #pragma unroll
            for (int n = 0; n < 4; ++n)
                acc[m][n] = __builtin_amdgcn_mfma_f32_16x16x32_bf16(af[m], bfv[n], acc[m][n], 0, 0, 0);
        if (t + 1 < nk) ST(cur ^ 1);
        __syncthreads();
    }

    const int orow = (lane >> 4) << 2;
    #pragma unroll
    for (int m = 0; m < 4; ++m) {
        int r0 = wr * 64 + m * 16 + orow;
        #pragma unroll
        for (int n = 0; n < 4; ++n) {
            int c = colBase + wc * 64 + n * 16 + fr;
            if (c < N) {
                float bv = bias ? bias[c] : 0.0f;
                #pragma unroll
                for (int r = 0; r < 4; ++r)
                    C[(size_t)(r0 + r) * N + c] = acc[m][n][r] + bv;
            }
        }
    }
}

// ---------------- self-attention (per (b,h) block) ----------------
__global__ __launch_bounds__(256) void attn_kernel(
    const u16* __restrict__ qkv, const float* __restrict__ rt, const int* __restrict__ rm,
    u16* __restrict__ ctxb)
{
    int bh = blockIdx.x;
    int b = bh >> 4, h = bh & 15;
    __shared__ float qs[S_][DK_ + 1], ks[S_][DK_ + 1], vs[S_][DK_ + 1];
    __shared__ float rts[5][DK_];
    __shared__ float Rs[S_][8];
    int tid = threadIdx.x;
    int wave = tid >> 6, lane = tid & 63;

    for (int idx = tid; idx < S_ * DK_; idx += 256) {
        int s = idx >> 6, d = idx & 63;
        size_t g = ((size_t)(b * S_ + s)) * (3 * D_) + h * DK_ + d;
        qs[s][d] = bf2f(qkv[g]);
        ks[s][d] = bf2f(qkv[g + D_]);
        vs[s][d] = bf2f(qkv[g + 2 * D_]);
    }
    for (int i = tid; i < 5 * DK_; i += 256)
        rts[i >> 6][i & 63] = rt[i];
    __syncthreads();

    for (int t = tid; t < S_ * 5; t += 256) {
        int i = t / 5, r = t - 5 * i;
        float a = 0.0f;
        #pragma unroll 8
        for (int d = 0; d < DK_; ++d) a += qs[i][d] * rts[r][d];
        Rs[i][r] = a;
    }
    __syncthreads();

    const float scale = 0.125f;
    for (int i = wave; i < S_; i += 4) {
        float sc = -INFINITY;
        if (lane < S_) {
            float acc = 0.0f;
            #pragma unroll 8
            for (int d = 0; d < DK_; ++d) acc += qs[i][d] * ks[lane][d];
            sc = acc * scale + 0.5f * Rs[i][rm[i * S_ + lane]];
        }
        float m = sc;
        #pragma unroll
        for (int off = 32; off; off >>= 1) m = fmaxf(m, __shfl_xor(m, off));
        float e = (lane < S_) ? expf(sc - m) : 0.0f;
        float sum = e;
        #pragma unroll
        for (int off = 32; off; off >>= 1) sum += __shfl_xor(sum, off);
        float aval = e / sum;

        float acc = 0.0f;
        for (int j = 0; j < S_; ++j) {
            float aj = __shfl(aval, j);
            acc += aj * vs[j][lane];
        }
        ctxb[((size_t)(b * S_ + i)) * D_ + h * DK_ + lane] = f2bf(acc);
    }
}

// ---------------- add + layernorm (bf16 residual, vectorized) ----------------
__global__ __launch_bounds__(256) void add_ln(
    const u16* __restrict__ a, const u16* __restrict__ res,
    const float* __restrict__ g, const float* __restrict__ be,
    u16* __restrict__ outb, float* __restrict__ outf)
{
    int row = blockIdx.x, tid = threadIdx.x;
    int c0 = tid << 2;
    ushort4 va = *reinterpret_cast<const ushort4*>(a   + (size_t)row * D_ + c0);
    ushort4 vr = *reinterpret_cast<const ushort4*>(res + (size_t)row * D_ + c0);
    float vals[4] = { bf2f(va.x) + bf2f(vr.x), bf2f(va.y) + bf2f(vr.y),
                      bf2f(va.z) + bf2f(vr.z), bf2f(va.w) + bf2f(vr.w) };
    float s = vals[0] + vals[1] + vals[2] + vals[3];
    __shared__ float red[8];
    #pragma unroll
    for (int off = 32; off; off >>= 1) s += __shfl_xor(s, off);
    int wave = tid >> 6, lane = tid & 63;
    if (lane == 0) red[wave] = s;
    __syncthreads();
    float mean = (red[0] + red[1] + red[2] + red[3]) * (1.0f / D_);
    float vv = 0.0f;
    #pragma unroll
    for (int t = 0; t < 4; ++t) {
        float d = vals[t] - mean;
        vv += d * d;
    }
    #pragma unroll
    for (int off = 32; off; off >>= 1) vv += __shfl_xor(vv, off);
    if (lane == 0) red[4 + wave] = vv;
    __syncthreads();
    float var = (red[4] + red[5] + red[6] + red[7]) * (1.0f / D_);
    float rstd = rsqrtf(var + 1e-5f);
    float4 gv  = *reinterpret_cast<const float4*>(g  + c0);
    float4 bev = *reinterpret_cast<const float4*>(be + c0);
    float o0 = (vals[0] - mean) * rstd * gv.x + bev.x;
    float o1 = (vals[1] - mean) * rstd * gv.y + bev.y;
    float o2 = (vals[2] - mean) * rstd * gv.z + bev.z;
    float o3 = (vals[3] - mean) * rstd * gv.w + bev.w;
    ushort4 ob;
    ob.x = f2bf(o0); ob.y = f2bf(o1); ob.z = f2bf(o2); ob.w = f2bf(o3);
    *reinterpret_cast<ushort4*>(outb + (size_t)row * D_ + c0) = ob;
    if (outf) {
        float4 of = { o0, o1, o2, o3 };
        *reinterpret_cast<float4*>(outf + (size_t)row * D_ + c0) = of;
    }
}

// ---------------- user embedding gather ----------------
__global__ __launch_bounds__(256) void gather_user(
    const float* __restrict__ ut, const int* __restrict__ ids,
    u16* __restrict__ o1, int ld1, u16* __restrict__ o2, int ld2)
{
    int b = blockIdx.x;
    int uid = ids[b];
    for (int d = threadIdx.x; d < D_; d += 256) {
        u16 v = f2bf(ut[(size_t)uid * D_ + d]);
        o1[(size_t)b * ld1 + d] = v;
        o2[(size_t)b * ld2 + d] = v;
    }
}

// ---------------- cross attention (q_len = 1); K/V merged [BS][2048] ----------------
__global__ __launch_bounds__(64) void cross_attn(
    const u16* __restrict__ qh, const u16* __restrict__ kv, u16* __restrict__ up)
{
    int bh = blockIdx.x;
    int b = bh >> 4, h = bh & 15;
    int lane = threadIdx.x;
    __shared__ float qv[DK_];
    qv[lane] = bf2f(qh[(size_t)b * D_ + h * DK_ + lane]);
    __syncthreads();
    float sc = -INFINITY;
    if (lane < S_) {
        float acc = 0.0f;
        const u16* krow = kv + ((size_t)(b * S_ + lane)) * 2048 + h * DK_;
        #pragma unroll 8
        for (int d = 0; d < DK_; ++d) acc += qv[d] * bf2f(krow[d]);
        sc = acc * 0.125f;
    }
    float m = sc;
    #pragma unroll
    for (int off = 32; off; off >>= 1) m = fmaxf(m, __shfl_xor(m, off));
    float e = (lane < S_) ? expf(sc - m) : 0.0f;
    float sum = e;
    #pragma unroll
    for (int off = 32; off; off >>= 1) sum += __shfl_xor(sum, off);
    float aval = e / sum;
    float acc = 0.0f;
    for (int j = 0; j < S_; ++j) {
        float aj = __shfl(aval, j);
        acc += aj * bf2f(kv[((size_t)(b * S_ + j)) * 2048 + 1024 + h * DK_ + lane]);
    }
    up[(size_t)b * D_ + h * DK_ + lane] = f2bf(acc);
}

// ---------------- sequence mean ----------------
__global__ __launch_bounds__(256) void seq_mean(
    const float* __restrict__ x,
    u16* __restrict__ o1, int ld1, u16* __restrict__ o2, int ld2)
{
    int b = blockIdx.x;
    for (int d = threadIdx.x; d < D_; d += 256) {
        float s = 0.0f;
        for (int si = 0; si < S_; ++si)
            s += x[((size_t)(b * S_ + si)) * D_ + d];
        u16 v = f2bf(s * (1.0f / S_));
        o1[(size_t)b * ld1 + d] = v;
        o2[(size_t)b * ld2 + d] = v;
    }
}

// ---------------- fused final heads ----------------
__global__ __launch_bounds__(256) void heads_final(
    const float* __restrict__ h1cn, const float* __restrict__ h1r, const float* __restrict__ ho,
    const float* __restrict__ c_w2, const float* __restrict__ c_b2,
    const float* __restrict__ r_w2, const float* __restrict__ r_b2,
    const float* __restrict__ o_w2, const float* __restrict__ o_b2,
    float* __restrict__ comp, float* __restrict__ rating, float* __restrict__ order)
{
    int b = blockIdx.x;
    int lane = threadIdx.x & 63, wv = threadIdx.x >> 6;
    if (wv == 0) {
        float s = 0.0f;
        for (int d = lane; d < D_; d += 64) s += h1cn[(size_t)b * 2048 + d] * c_w2[d];
        #pragma unroll
        for (int off = 32; off; off >>= 1) s += __shfl_xor(s, off);
        if (lane == 0) comp[b] = 1.0f / (1.0f + expf(-(s + c_b2[0])));
    } else if (wv == 1) {
        float s = 0.0f;
        for (int d = lane; d < D_; d += 64) s += h1r[(size_t)b * D_ + d] * r_w2[d];
        #pragma unroll
        for (int off = 32; off; off >>= 1) s += __shfl_xor(s, off);
        if (lane == 0) rating[b] = s + r_b2[0];
    } else if (wv == 2) {
        float s0 = 0.0f, s1 = 0.0f;
        for (int d = lane; d < 512; d += 64) {
            float hv = ho[(size_t)b * 512 + d];
            s0 += hv * o_w2[d * 2];
            s1 += hv * o_w2[d * 2 + 1];
        }
        #pragma unroll
        for (int off = 32; off; off >>= 1) { s0 += __shfl_xor(s0, off); s1 += __shfl_xor(s1, off); }
        if (lane == 0) {
            float a = s0 + o_b2[0], c = s1 + o_b2[1];
            float m = fmaxf(a, c);
            float ea = expf(a - m), ec = expf(c - m);
            float s = ea + ec;
            order[b * 2] = ea / s;
            order[b * 2 + 1] = ec / s;
        }
    }
}

// ---------------- host-side launcher ----------------
extern "C" void kernel_launch(void* const* d_in, const int* in_sizes, int n_in,
                              void* d_out, int out_size, void* d_ws, size_t ws_size,
                              hipStream_t stream) {
    const float* movie_table = (const float*)d_in[0];
    const float* fran_table  = (const float*)d_in[1];
    const float* entry_table = (const float*)d_in[2];
    const float* proj_w      = (const float*)d_in[3];
    const float* proj_b      = (const float*)d_in[4];
    const float* wq          = (const float*)d_in[5];
    const float* bq          = (const float*)d_in[6];
    const float* wk          = (const float*)d_in[7];
    const float* bk          = (const float*)d_in[8];
    const float* wv          = (const float*)d_in[9];
    const float* bv          = (const float*)d_in[10];
    const float* wo          = (const float*)d_in[11];
    const float* bo          = (const float*)d_in[12];
    const float* rel_table   = (const float*)d_in[13];
    const float* aln_g       = (const float*)d_in[14];
    const float* aln_b       = (const float*)d_in[15];
    const float* f_w1        = (const float*)d_in[16];
    const float* f_b1        = (const float*)d_in[17];
    const float* f_w2        = (const float*)d_in[18];
    const float* f_b2        = (const float*)d_in[19];
    const float* ln_g        = (const float*)d_in[20];
    const float* ln_b        = (const float*)d_in[21];
    const float* user_table  = (const float*)d_in[22];
    const float* mq_w        = (const float*)d_in[23];
    const float* mq_b        = (const float*)d_in[24];
    const float* mk_w        = (const float*)d_in[25];
    const float* mk_b        = (const float*)d_in[26];
    const float* mv_w        = (const float*)d_in[27];
    const float* mv_b        = (const float*)d_in[28];
    const float* mo_w        = (const float*)d_in[29];
    const float* mo_b        = (const float*)d_in[30];
    const float* c_w1        = (const float*)d_in[31];
    const float* c_b1        = (const float*)d_in[32];
    const float* c_w2        = (const float*)d_in[33];
    const float* c_b2        = (const float*)d_in[34];
    const float* n_w1        = (const float*)d_in[35];
    const float* n_b1        = (const float*)d_in[36];
    const float* n_w2        = (const float*)d_in[37];
    const float* n_b2        = (const float*)d_in[38];
    const float* r_w1        = (const float*)d_in[39];
    const float* r_b1        = (const float*)d_in[40];
    const float* r_w2        = (const float*)d_in[41];
    const float* r_b2        = (const float*)d_in[42];
    const float* o_w1        = (const float*)d_in[43];
    const float* o_b1        = (const float*)d_in[44];
    const float* o_w2        = (const float*)d_in[45];
    const float* o_b2        = (const float*)d_in[46];
    const int* user_ids      = (const int*)d_in[47];
    const int* movie_ids     = (const int*)d_in[48];
    const int* franchise_ids = (const int*)d_in[49];
    const int* entry_types   = (const int*)d_in[50];
    const int* relation_mat  = (const int*)d_in[51];

    // ---- workspace layout (u16 units) ----
    u16* up16 = (u16*)d_ws;
    u16* proj_wt = up16;                                   // [1024][1536]
    u16* wqkv_t  = proj_wt + (size_t)1024 * 1536;          // [4][3072][1024]
    u16* wo_t    = wqkv_t  + (size_t)4 * 3072 * 1024;      // [4][1024][1024]
    u16* fw1_buf = wo_t    + (size_t)4 * 1024 * 1024;      // [4096][1024]
    u16* fw2_buf = fw1_buf + (size_t)4096 * 1024;          // [1024][4096]
    u16* mq_t    = fw2_buf + (size_t)1024 * 4096;          // [1024][1024]
    u16* mk_t    = mq_t    + (size_t)1024 * 1024;          // mk|mv = [2048][1024]
    u16* mv_t    = mk_t    + (size_t)1024 * 1024;
    u16* mo_t    = mv_t    + (size_t)1024 * 1024;
    u16* cn_w1t  = mo_t    + (size_t)1024 * 1024;          // [2048][2048]
    u16* r_w1t   = cn_w1t  + (size_t)2048 * 2048;          // [1024][3072]
    u16* o_w1t   = r_w1t   + (size_t)1024 * 3072;          // [512][1024]
    u16* ffb     = o_w1t   + (size_t)512 * 1024;           // [6400][4096]
    u16* xinb    = ffb;                                    // [6400][1536] (dead after proj)
    u16* xb      = ffb     + (size_t)BS_ * FF_;            // [6400][1024]
    u16* xb2     = xb      + (size_t)BS_ * D_;             // [6400][1024]
    u16* qkvb    = xb2     + (size_t)BS_ * D_;             // [6400][3072]
    u16* kvb     = qkvb    + (size_t)BS_ * 3 * D_;         // [6400][2048]
    u16* ctxb    = kvb;
    u16* ob      = kvb     + (size_t)BS_ * D_;
    u16* ueb     = kvb     + (size_t)BS_ * 2 * D_;         // [128][1024]
    u16* upb_pre = ueb     + (size_t)B_ * D_;              // [128][1024]
    u16* cib     = upb_pre + (size_t)B_ * D_;              // [128][2048]
    u16* rib     = cib     + (size_t)B_ * 2 * D_;          // [128][3072]
    float* fp    = (float*)(rib + (size_t)B_ * 3 * D_);
    float* bqkv  = fp;                                     // [4][3072]
    float* bcn   = bqkv + 4 * 3072;                        // [2048]
    float* bkv   = bcn  + 2048;                            // [2048]
    float* pet   = bkv  + 2048;                            // [50][1024]
    float* h1cn  = pet  + 50 * 1024;                       // [128][2048]
    float* h1r   = h1cn + (size_t)B_ * 2048;               // [128][1024]
    float* ho    = h1r  + (size_t)B_ * D_;                 // [128][512]

    // ---- d_out layout ----
    float* xout    = (float*)d_out;                 // [BS, D]
    float* comp    = xout + (size_t)BS_ * D_;       // [B,1]
    float* logits  = comp + B_;                     // [B,V]
    float* rating  = logits + (size_t)B_ * V_;      // [B,1]
    float* order   = rating + B_;                   // [B,2]
    float* upref   = order + 2 * B_;                // [B,D]

    dim3 blk(256);
    dim3 blk512(512);

    // ---- weight conversion pass ----
    wtrans<<<dim3(32, 48, 1), blk, 0, stream>>>(proj_w, proj_wt, 1536, 1024, 0, 0, 0);
    wtrans_qkv<<<dim3(32, 32, 12), blk, 0, stream>>>(wq, wk, wv, wqkv_t);
    WT8 w8;
    w8.s[0] = wo;                 w8.d[0] = wo_t;
    w8.s[1] = wo + 1048576;       w8.d[1] = wo_t + 1048576;
    w8.s[2] = wo + 2097152;       w8.d[2] = wo_t + 2097152;
    w8.s[3] = wo + 3145728;       w8.d[3] = wo_t + 3145728;
    w8.s[4] = mq_w;               w8.d[4] = mq_t;
    w8.s[5] = mk_w;               w8.d[5] = mk_t;
    w8.s[6] = mv_w;               w8.d[6] = mv_t;
    w8.s[7] = mo_w;               w8.d[7] = mo_t;
    wtrans8<<<dim3(32, 32, 8), blk, 0, stream>>>(w8);
    wtrans<<<dim3(32, 64, 1), blk, 0, stream>>>(c_w1, cn_w1t, 2048, 1024, 0, 0, 0);
    wtrans<<<dim3(32, 64, 1), blk, 0, stream>>>(n_w1, cn_w1t, 2048, 1024, 0, 0, 1024);
    wtrans<<<dim3(32, 96, 1), blk, 0, stream>>>(r_w1, r_w1t, 3072, 1024, 0, 0, 0);
    wtrans<<<dim3(16, 32, 1), blk, 0, stream>>>(o_w1, o_w1t, 1024, 512, 0, 0, 0);
    setup_misc<<<dim3(56), blk, 0, stream>>>(bq, bk, bv, c_b1, n_b1, mk_b, mv_b,
                                             bqkv, bcn, bkv, pet);

    // ---- encoder input: 256^2 proj with fused bias+PE ----
    embed_concat<<<BS_, blk, 0, stream>>>(movie_table, fran_table, entry_table,
                                          movie_ids, franchise_ids, entry_types, xinb);
    gemm256<<<dim3(4, 25), blk512, 0, stream>>>(xinb, 1536, proj_wt, proj_b,
                                                xb, 1024, D_, 1536, 0, pet);

    // ---- transformer layers (x ping-pong: xb -> xb2 -> xb) ----
    for (int l = 0; l < L_; ++l) {
        gemm256<<<dim3(12, 25), blk512, 0, stream>>>(xb, 1024,
                wqkv_t + (size_t)l * 3145728, bqkv + l * 3072,
                qkvb, 3072, 3 * D_, D_, 0, nullptr);
        attn_kernel<<<B_ * H_, blk, 0, stream>>>(qkvb, rel_table + (size_t)l * 5 * DK_,
                                                 relation_mat, ctxb);
        gemm256<<<dim3(4, 25), blk512, 0, stream>>>(ctxb, 1024,
                wo_t + (size_t)l * 1048576, bo + l * D_,
                ob, 1024, D_, D_, 0, nullptr);
        add_ln<<<BS_, blk, 0, stream>>>(ob, xb, aln_g + l * D_, aln_b + l * D_, xb2, nullptr);
        wtrans_ff<<<dim3(128, 32, 2), blk, 0, stream>>>(f_w1 + (size_t)l * D_ * FF_,
                                                        f_w2 + (size_t)l * FF_ * D_,
                                                        fw1_buf, fw2_buf);
        gemm256<<<dim3(16, 25), blk512, 0, stream>>>(xb2, 1024, fw1_buf, f_b1 + l * FF_,
                ffb, 4096, FF_, D_, 1, nullptr);
        gemm256<<<dim3(4, 25), blk512, 0, stream>>>(ffb, 4096, fw2_buf, f_b2 + l * D_,
                ob, 1024, D_, FF_, 0, nullptr);
        add_ln<<<BS_, blk, 0, stream>>>(ob, xb2, ln_g + l * D_, ln_b + l * D_, xb,
                                        (l == L_ - 1) ? xout : nullptr);
    }

    // ---- user cross-attention ----
    gather_user<<<B_, blk, 0, stream>>>(user_table, user_ids, ueb, 1024, rib, 3072);
    gemm_bf16_t<64><<<dim3(8, 2), blk, 0, stream>>>(ueb, 1024, mq_t, mq_b,
            nullptr, qkvb, 1024, nullptr, 0, D_, D_, 0);
    gemm256<<<dim3(8, 25), blk512, 0, stream>>>(xb, 1024, mk_t, bkv,
            kvb, 2048, 2 * D_, D_, 0, nullptr);
    cross_attn<<<B_ * H_, dim3(64), 0, stream>>>(qkvb, kvb, upb_pre);
    gemm_bf16_t<64><<<dim3(8, 2), blk, 0, stream>>>(upb_pre, 1024, mo_t, mo_b,
            upref, cib, 2048, rib + 1024, 3072, D_, D_, 0);

    // ---- sequence mean (writes into both concats) ----
    seq_mean<<<B_, blk, 0, stream>>>(xout, cib + 1024, 2048, rib + 2048, 3072);

    // ---- heads ----
    gemm_bf16_t<64><<<dim3(16, 2), blk, 0, stream>>>(cib, 2048, cn_w1t, bcn,
            h1cn, nullptr, 0, nullptr, 0, 2048, 2048, 1);
    gemm_bf16_t<64><<<dim3(8, 2), blk, 0, stream>>>(rib, 3072, r_w1t, r_b1,
            h1r, nullptr, 0, nullptr, 0, D_, 3072, 1);
    gemm_bf16_t<64><<<dim3(4, 2), blk, 0, stream>>>(cib, 2048, o_w1t, o_b1,
            ho, nullptr, 0, nullptr, 0, 512, D_, 1);
    gemm_logits<<<dim3(782, 1), blk, 0, stream>>>(h1cn + 1024, 2048, n_w2, n_b2,
                                                  logits, V_, D_);
    heads_final<<<B_, blk, 0, stream>>>(h1cn, h1r, ho, c_w2, c_b2, r_w2, r_b2,
                                        o_w2, o_b2, comp, rating, order);
}

// Round 11
// 2129.795 us; speedup vs baseline: 1.1076x; 1.1076x over previous
//
#include <hip/hip_runtime.h>
#include <hip/hip_bf16.h>
#include <math.h>

// ---------------- problem constants ----------------
#define B_   128
#define S_   50
#define BS_  (B_*S_)        // 6400
#define E_   512
#define D_   1024
#define H_   16
#define DK_  64
#define L_   4
#define FF_  4096
#define V_   100000

typedef short bf8_t __attribute__((ext_vector_type(8)));
typedef float f32x4 __attribute__((ext_vector_type(4)));
typedef float f32x16 __attribute__((ext_vector_type(16)));
typedef unsigned short u16;

__device__ __forceinline__ float gelu_exact(float x) {
    return 0.5f * x * (1.0f + erff(x * 0.70710678118654752440f));
}
__device__ __forceinline__ u16 f2bf(float f) {
    unsigned int u = __float_as_uint(f);
    return (u16)((u + 0x7FFFu + ((u >> 16) & 1u)) >> 16);
}
__device__ __forceinline__ float bf2f(u16 u) {
    return __uint_as_float(((unsigned int)u) << 16);
}

// async global->LDS, 16B per lane
__device__ __forceinline__ void gload16(const u16* g, u16* l) {
    auto* g1 = reinterpret_cast<const __attribute__((address_space(1))) unsigned int*>(
                   reinterpret_cast<uintptr_t>(g));
    auto* l3 = reinterpret_cast<__attribute__((address_space(3))) unsigned int*>(
                   reinterpret_cast<uintptr_t>(l));
    __builtin_amdgcn_global_load_lds(g1, l3, 16, 0, 0);
}

// ---------------- weight transpose bodies ----------------
__device__ __forceinline__ void wtrans_body(
    const float* __restrict__ W, u16* __restrict__ Wt,
    int K, int N, int nb, int kb, int dstRowOff)
{
    __shared__ float t[32][33];
    int c = threadIdx.x & 31, r0 = threadIdx.x >> 5;
    #pragma unroll
    for (int rr = 0; rr < 32; rr += 8)
        t[rr + r0][c] = W[(size_t)(kb + rr + r0) * N + nb + c];
    __syncthreads();
    #pragma unroll
    for (int rr = 0; rr < 32; rr += 8)
        Wt[(size_t)(dstRowOff + nb + rr + r0) * K + kb + c] = f2bf(t[c][rr + r0]);
}

__global__ __launch_bounds__(256) void wtrans(
    const float* __restrict__ W, u16* __restrict__ Wt,
    int K, int N, long srcLS, long dstLS, int dstRowOff)
{
    int l = blockIdx.z;
    wtrans_body(W + (size_t)l * srcLS, Wt + (size_t)l * dstLS,
                K, N, blockIdx.x * 32, blockIdx.y * 32, dstRowOff);
}

__global__ __launch_bounds__(256) void wtrans_qkv(
    const float* __restrict__ wq, const float* __restrict__ wk, const float* __restrict__ wv,
    u16* __restrict__ dst)
{
    int z = blockIdx.z;
    int l = z & 3, which = z >> 2;
    const float* W = (which == 0 ? wq : which == 1 ? wk : wv) + (size_t)l * (D_ * D_);
    u16* Wt = dst + (size_t)l * (3 * D_ * D_) + (size_t)which * (D_ * D_);
    wtrans_body(W, Wt, D_, D_, blockIdx.x * 32, blockIdx.y * 32, 0);
}

struct WT8 { const float* s[8]; u16* d[8]; };
__global__ __launch_bounds__(256) void wtrans8(WT8 p)
{
    int z = blockIdx.z;
    wtrans_body(p.s[z], p.d[z], D_, D_, blockIdx.x * 32, blockIdx.y * 32, 0);
}

__global__ __launch_bounds__(256) void wtrans_ff(
    const float* __restrict__ w1, const float* __restrict__ w2,
    u16* __restrict__ d1, u16* __restrict__ d2)
{
    if (blockIdx.z == 0)
        wtrans_body(w1, d1, D_, FF_, blockIdx.x * 32, blockIdx.y * 32, 0);
    else
        wtrans_body(w2, d2, FF_, D_, blockIdx.y * 32, blockIdx.x * 32, 0);
}

// ---------------- embedding gather + concat (bf16 out) ----------------
__global__ __launch_bounds__(256) void embed_concat(
    const float* __restrict__ mt, const float* __restrict__ ft, const float* __restrict__ et,
    const int* __restrict__ mids, const int* __restrict__ fids, const int* __restrict__ eids,
    u16* __restrict__ xinb)
{
    int bs = blockIdx.x;
    int mid = mids[bs], fid = fids[bs], eid = eids[bs];
    const float* srcs[3] = { mt + (size_t)mid * E_, ft + (size_t)fid * E_, et + (size_t)eid * E_ };
    u16* dst = xinb + (size_t)bs * (3 * E_);
    for (int i = threadIdx.x; i < 384; i += 256) {
        int seg = i >> 7, off = i & 127;
        float4 v = reinterpret_cast<const float4*>(srcs[seg])[off];
        ushort4 b;
        b.x = f2bf(v.x); b.y = f2bf(v.y); b.z = f2bf(v.z); b.w = f2bf(v.w);
        reinterpret_cast<ushort4*>(dst + seg * E_)[off] = b;
    }
}

// ---------------- setup misc: bias concats + PE table ----------------
__global__ __launch_bounds__(256) void setup_misc(
    const float* __restrict__ bq, const float* __restrict__ bk, const float* __restrict__ bv,
    const float* __restrict__ cb1, const float* __restrict__ nb1,
    const float* __restrict__ mkb, const float* __restrict__ mvb,
    float* __restrict__ bqkv, float* __restrict__ bcn, float* __restrict__ bkv,
    float* __restrict__ pet)
{
    int bi = blockIdx.x, tid = threadIdx.x;
    if (bi < 4) {
        for (int c = tid; c < 3072; c += 256) {
            float v = (c < 1024) ? bq[bi * 1024 + c]
                    : (c < 2048) ? bk[bi * 1024 + c - 1024]
                                 : bv[bi * 1024 + c - 2048];
            bqkv[bi * 3072 + c] = v;
        }
    } else if (bi == 4) {
        for (int c = tid; c < 2048; c += 256)
            bcn[c] = (c < 1024) ? cb1[c] : nb1[c - 1024];
    } else if (bi == 5) {
        for (int c = tid; c < 2048; c += 256)
            bkv[c] = (c < 1024) ? mkb[c] : mvb[c - 1024];
    } else {
        int s = bi - 6;
        const float cc = -logf(10000.0f) / 512.0f;
        for (int d = tid; d < D_; d += 256) {
            int second = d >= 512;
            int c2 = second ? d - 512 : d;
            int i = c2 >> 1;
            float div = expf(cc * (float)(2 * i));
            float aa = (float)s * div * (second ? 1.5f : 1.0f);
            pet[s * D_ + d] = (c2 & 1) ? cosf(aa) : sinf(aa);
        }
    }
}

// ---------------- 128x128 / 4-wave GEMM, 32x32x16 MFMA, depth-2 counted vmcnt ----------------
// A bf16 [M,lda], Wt bf16 [N,K] row-major, bias fp32[N]. M%128==0, N%128==0, K%32==0, nk>=2.
// grid (N/128, M/128). Each wave: 64x64 output = 2x2 of 32x32 MFMA tiles.
__global__ __launch_bounds__(256) void gemm128_w32(
    const u16* __restrict__ A, int lda, const u16* __restrict__ Wt,
    const float* __restrict__ bias,
    u16* __restrict__ Cb, int ldcb,
    int N, int K, int act)
{
    __shared__ u16 As[2 * 4096];
    __shared__ u16 Bs[2 * 4096];
    const int tid  = threadIdx.x;
    const int lane = tid & 63;
    const int wid  = tid >> 6;
    const int wr   = wid >> 1, wc = wid & 1;

    // XCD-bijective swizzle (m204)
    const int gx  = gridDim.x;
    const int nwg = gx * gridDim.y;
    int orig = blockIdx.y * gx + blockIdx.x;
    int qq = nwg >> 3, rr2 = nwg & 7, xcd = orig & 7, idx = orig >> 3;
    int wgid = (xcd < rr2) ? (xcd * (qq + 1) + idx)
                           : (rr2 * (qq + 1) + (xcd - rr2) * qq + idx);
    const int rowBase = (wgid / gx) * 128;
    const int colBase = (wgid % gx) * 128;

    // staging geometry (identical to r8 BM=128 path)
    const int sRowL  = lane >> 2;
    const int sChunk = lane & 3;
    const int gRow0  = (wid << 5) + sRowL;
    const int skey   = (gRow0 >> 1) & 3;           // same for gRow0+16
    const int gC     = (sChunk ^ skey) << 3;
    const u16* aS0 = A  + (size_t)(rowBase + gRow0) * lda + gC;
    const u16* aS1 = aS0 + (size_t)16 * lda;
    const u16* bS0 = Wt + (size_t)(colBase + gRow0) * K + gC;
    const u16* bS1 = bS0 + (size_t)16 * K;
    const int ldsW0 = (wid << 5) << 5;
    const int ldsW1 = ldsW0 + (16 << 5);

    // 32x32x16 fragment geometry: A row = l31, k = hi5*8 + i (per K=16 sub-step)
    const int l31 = lane & 31;
    const int hi5 = lane >> 5;
    const int key32 = (l31 >> 1) & 3;
    const int c0 = (0 | hi5) ^ key32;             // chunk for ks=0
    const int c1 = (2 | hi5) ^ key32;             // chunk for ks=1
    const int aB0 = (wr * 64 + l31) * 32;
    const int bB0 = (wc * 64 + l31) * 32;

    f32x16 acc[2][2] = {};
    const int nk = K >> 5;

    auto STAGE = [&](int kb, int buf) {
        u16* dA = As + buf * 4096;
        u16* dB = Bs + buf * 4096;
        gload16(aS0 + kb, dA + ldsW0);
        gload16(aS1 + kb, dA + ldsW1);
        gload16(bS0 + kb, dB + ldsW0);
        gload16(bS1 + kb, dB + ldsW1);
    };

    STAGE(0, 0);
    __builtin_amdgcn_sched_barrier(0);
    STAGE(32, 1);
    __builtin_amdgcn_sched_barrier(0);
    asm volatile("s_waitcnt vmcnt(4)\n\ts_barrier" ::: "memory");
    __builtin_amdgcn_sched_barrier(0);

    for (int t = 0; t < nk; ++t) {
        const int cur = t & 1;
        const u16* bA = As + cur * 4096;
        const u16* bB = Bs + cur * 4096;
        bf8_t aF[2][2], bF[2][2];
        #pragma unroll
        for (int mi = 0; mi < 2; ++mi) {
            aF[mi][0] = *reinterpret_cast<const bf8_t*>(&bA[aB0 + mi * 1024 + c0 * 8]);
            aF[mi][1] = *reinterpret_cast<const bf8_t*>(&bA[aB0 + mi * 1024 + c1 * 8]);
        }
        #pragma unroll
        for (int ni = 0; ni < 2; ++ni) {
            bF[ni][0] = *reinterpret_cast<const bf8_t*>(&bB[bB0 + ni * 1024 + c0 * 8]);
            bF[ni][1] = *reinterpret_cast<const bf8_t*>(&bB[bB0 + ni * 1024 + c1 * 8]);
        }
        #pragma unroll
        for (int mi = 0; mi < 2; ++mi)
            #pragma unroll
            for (int ni = 0; ni < 2; ++ni) {
                acc[mi][ni] = __builtin_amdgcn_mfma_f32_32x32x16_bf16(aF[mi][0], bF[ni][0], acc[mi][ni], 0, 0, 0);
                acc[mi][ni] = __builtin_amdgcn_mfma_f32_32x32x16_bf16(aF[mi][1], bF[ni][1], acc[mi][ni], 0, 0, 0);
            }
        if (t == nk - 1) break;
        __builtin_amdgcn_sched_barrier(0);
        asm volatile("s_waitcnt lgkmcnt(0)\n\ts_barrier" ::: "memory");
        __builtin_amdgcn_sched_barrier(0);
        if (t + 2 < nk) {
            STAGE((t + 2) << 5, cur);
            __builtin_amdgcn_sched_barrier(0);
            asm volatile("s_waitcnt vmcnt(4)\n\ts_barrier" ::: "memory");
        } else {
            asm volatile("s_waitcnt vmcnt(0)\n\ts_barrier" ::: "memory");
        }
        __builtin_amdgcn_sched_barrier(0);
    }

    // epilogue: 32x32 C/D map col=lane&31, row=(reg&3)+8*(reg>>2)+4*(lane>>5)
    #pragma unroll
    for (int mi = 0; mi < 2; ++mi) {
        int rt = rowBase + wr * 64 + mi * 32 + 4 * hi5;
        #pragma unroll
        for (int ni = 0; ni < 2; ++ni) {
            int ct = colBase + wc * 64 + ni * 32 + l31;
            float bv = bias ? bias[ct] : 0.0f;
            #pragma unroll
            for (int r = 0; r < 16; ++r) {
                int rr = rt + (r & 3) + 8 * (r >> 2);
                float v = acc[mi][ni][r] + bv;
                if (act == 1) v = gelu_exact(v);
                Cb[(size_t)rr * ldcb + ct] = f2bf(v);
            }
        }
    }
}

// ---------------- split-K GEMM: bf16 partials, 32x32 MFMA, grid (N/128, M/128, 2) ----------------
__global__ __launch_bounds__(256) void gemm_sk32(
    const u16* __restrict__ A, int lda, const u16* __restrict__ Wt, int ldb,
    u16* __restrict__ P0, u16* __restrict__ P1,
    int N, int Kh)
{
    __shared__ u16 As[2 * 4096];
    __shared__ u16 Bs[2 * 4096];
    const int tid  = threadIdx.x;
    const int lane = tid & 63;
    const int wid  = tid >> 6;
    const int wr   = wid >> 1, wc = wid & 1;

    const int gx  = gridDim.x;
    const int nwg = gx * gridDim.y;
    int orig = blockIdx.y * gx + blockIdx.x;
    int qq = nwg >> 3, rr2 = nwg & 7, xcd = orig & 7, idx = orig >> 3;
    int wgid = (xcd < rr2) ? (xcd * (qq + 1) + idx)
                           : (rr2 * (qq + 1) + (xcd - rr2) * qq + idx);
    const int rowBase = (wgid / gx) * 128;
    const int colBase = (wgid % gx) * 128;
    const int k0 = blockIdx.z * Kh;
    u16* P = blockIdx.z ? P1 : P0;

    const int sRowL  = lane >> 2;
    const int sChunk = lane & 3;
    const int gRow0  = (wid << 5) + sRowL;
    const int skey   = (gRow0 >> 1) & 3;
    const int gC     = (sChunk ^ skey) << 3;
    const u16* aS0 = A  + (size_t)(rowBase + gRow0) * lda + k0 + gC;
    const u16* aS1 = aS0 + (size_t)16 * lda;
    const u16* bS0 = Wt + (size_t)(colBase + gRow0) * ldb + k0 + gC;
    const u16* bS1 = bS0 + (size_t)16 * ldb;
    const int ldsW0 = (wid << 5) << 5;
    const int ldsW1 = ldsW0 + (16 << 5);

    const int l31 = lane & 31;
    const int hi5 = lane >> 5;
    const int key32 = (l31 >> 1) & 3;
    const int c0 = (0 | hi5) ^ key32;
    const int c1 = (2 | hi5) ^ key32;
    const int aB0 = (wr * 64 + l31) * 32;
    const int bB0 = (wc * 64 + l31) * 32;

    f32x16 acc[2][2] = {};
    const int nk = Kh >> 5;

    auto STAGE = [&](int kb, int buf) {
        u16* dA = As + buf * 4096;
        u16* dB = Bs + buf * 4096;
        gload16(aS0 + kb, dA + ldsW0);
        gload16(aS1 + kb, dA + ldsW1);
        gload16(bS0 + kb, dB + ldsW0);
        gload16(bS1 + kb, dB + ldsW1);
    };

    STAGE(0, 0);
    __builtin_amdgcn_sched_barrier(0);
    STAGE(32, 1);
    __builtin_amdgcn_sched_barrier(0);
    asm volatile("s_waitcnt vmcnt(4)\n\ts_barrier" ::: "memory");
    __builtin_amdgcn_sched_barrier(0);

    for (int t = 0; t < nk; ++t) {
        const int cur = t & 1;
        const u16* bA = As + cur * 4096;
        const u16* bB = Bs + cur * 4096;
        bf8_t aF[2][2], bF[2][2];
        #pragma unroll
        for (int mi = 0; mi < 2; ++mi) {
            aF[mi][0] = *reinterpret_cast<const bf8_t*>(&bA[aB0 + mi * 1024 + c0 * 8]);
            aF[mi][1] = *reinterpret_cast<const bf8_t*>(&bA[aB0 + mi * 1024 + c1 * 8]);
        }
        #pragma unroll
        for (int ni = 0; ni < 2; ++ni) {
            bF[ni][0] = *reinterpret_cast<const bf8_t*>(&bB[bB0 + ni * 1024 + c0 * 8]);
            bF[ni][1] = *reinterpret_cast<const bf8_t*>(&bB[bB0 + ni * 1024 + c1 * 8]);
        }
        #pragma unroll
        for (int mi = 0; mi < 2; ++mi)
            #pragma unroll
            for (int ni = 0; ni < 2; ++ni) {
                acc[mi][ni] = __builtin_amdgcn_mfma_f32_32x32x16_bf16(aF[mi][0], bF[ni][0], acc[mi][ni], 0, 0, 0);
                acc[mi][ni] = __builtin_amdgcn_mfma_f32_32x32x16_bf16(aF[mi][1], bF[ni][1], acc[mi][ni], 0, 0, 0);
            }
        if (t == nk - 1) break;
        __builtin_amdgcn_sched_barrier(0);
        asm volatile("s_waitcnt lgkmcnt(0)\n\ts_barrier" ::: "memory");
        __builtin_amdgcn_sched_barrier(0);
        if (t + 2 < nk) {
            STAGE((t + 2) << 5, cur);
            __builtin_amdgcn_sched_barrier(0);
            asm volatile("s_waitcnt vmcnt(4)\n\ts_barrier" ::: "memory");
        } else {
            asm volatile("s_waitcnt vmcnt(0)\n\ts_barrier" ::: "memory");
        }
        __builtin_amdgcn_sched_barrier(0);
    }

    #pragma unroll
    for (int mi = 0; mi < 2; ++mi) {
        int rt = rowBase + wr * 64 + mi * 32 + 4 * hi5;
        #pragma unroll
        for (int ni = 0; ni < 2; ++ni) {
            int ct = colBase + wc * 64 + ni * 32 + l31;
            #pragma unroll
            for (int r = 0; r < 16; ++r) {
                int rr = rt + (r & 3) + 8 * (r >> 2);
                P[(size_t)rr * N + ct] = f2bf(acc[mi][ni][r]);
            }
        }
    }
}

// ---------------- combine: xb = bf16(p1 + p2 + bias + pe) ----------------
__global__ __launch_bounds__(256) void combine_bias_pe(
    const u16* __restrict__ p1, const u16* __restrict__ p2,
    const float* __restrict__ bias, const float* __restrict__ pe,
    u16* __restrict__ outb)
{
    int row = blockIdx.x, tid = threadIdx.x;
    int c0 = tid << 2;
    size_t base = (size_t)row * D_ + c0;
    ushort4 v1 = *reinterpret_cast<const ushort4*>(p1 + base);
    ushort4 v2 = *reinterpret_cast<const ushort4*>(p2 + base);
    float4 bv = *reinterpret_cast<const float4*>(bias + c0);
    float4 pv = *reinterpret_cast<const float4*>(pe + (size_t)(row % S_) * D_ + c0);
    ushort4 ob;
    ob.x = f2bf(bf2f(v1.x) + bf2f(v2.x) + bv.x + pv.x);
    ob.y = f2bf(bf2f(v1.y) + bf2f(v2.y) + bv.y + pv.y);
    ob.z = f2bf(bf2f(v1.z) + bf2f(v2.z) + bv.z + pv.z);
    ob.w = f2bf(bf2f(v1.w) + bf2f(v2.w) + bv.w + pv.w);
    *reinterpret_cast<ushort4*>(outb + base) = ob;
}

// ---------------- combine + add + layernorm: out = LN(p1+p2+bias + res) ----------------
__global__ __launch_bounds__(256) void add_ln2(
    const u16* __restrict__ p1, const u16* __restrict__ p2,
    const float* __restrict__ bias, const u16* __restrict__ res,
    const float* __restrict__ g, const float* __restrict__ be,
    u16* __restrict__ outb, float* __restrict__ outf)
{
    int row = blockIdx.x, tid = threadIdx.x;
    int c0 = tid << 2;
    size_t base = (size_t)row * D_ + c0;
    ushort4 v1 = *reinterpret_cast<const ushort4*>(p1 + base);
    ushort4 v2 = *reinterpret_cast<const ushort4*>(p2 + base);
    float4 bv = *reinterpret_cast<const float4*>(bias + c0);
    ushort4 vr = *reinterpret_cast<const ushort4*>(res + base);
    float vals[4] = { bf2f(v1.x) + bf2f(v2.x) + bv.x + bf2f(vr.x),
                      bf2f(v1.y) + bf2f(v2.y) + bv.y + bf2f(vr.y),
                      bf2f(v1.z) + bf2f(v2.z) + bv.z + bf2f(vr.z),
                      bf2f(v1.w) + bf2f(v2.w) + bv.w + bf2f(vr.w) };
    float s = vals[0] + vals[1] + vals[2] + vals[3];
    __shared__ float red[8];
    #pragma unroll
    for (int off = 32; off; off >>= 1) s += __shfl_xor(s, off);
    int wave = tid >> 6, lane = tid & 63;
    if (lane == 0) red[wave] = s;
    __syncthreads();
    float mean = (red[0] + red[1] + red[2] + red[3]) * (1.0f / D_);
    float vv = 0.0f;
    #pragma unroll
    for (int t = 0; t < 4; ++t) {
        float d = vals[t] - mean;
        vv += d * d;
    }
    #pragma unroll
    for (int off = 32; off; off >>= 1) vv += __shfl_xor(vv, off);
    if (lane == 0) red[4 + wave] = vv;
    __syncthreads();
    float var = (red[4] + red[5] + red[6] + red[7]) * (1.0f / D_);
    float rstd = rsqrtf(var + 1e-5f);
    float4 gv  = *reinterpret_cast<const float4*>(g  + c0);
    float4 bev = *reinterpret_cast<const float4*>(be + c0);
    float o0 = (vals[0] - mean) * rstd * gv.x + bev.x;
    float o1 = (vals[1] - mean) * rstd * gv.y + bev.y;
    float o2 = (vals[2] - mean) * rstd * gv.z + bev.z;
    float o3 = (vals[3] - mean) * rstd * gv.w + bev.w;
    ushort4 ob;
    ob.x = f2bf(o0); ob.y = f2bf(o1); ob.z = f2bf(o2); ob.w = f2bf(o3);
    *reinterpret_cast<ushort4*>(outb + base) = ob;
    if (outf) {
        float4 of = { o0, o1, o2, o3 };
        *reinterpret_cast<float4*>(outf + base) = of;
    }
}

// ---------------- small bf16 GEMM (M=128 heads), BM=64, 16x16 MFMA ----------------
template<int BM>
__global__ __launch_bounds__(256) void gemm_bf16_t(
    const u16* __restrict__ A, int lda, const u16* __restrict__ Wt,
    const float* __restrict__ bias, float* __restrict__ Cf,
    u16* __restrict__ Cb, int ldcb, u16* __restrict__ Cb2, int ldcb2,
    int N, int K, int act)
{
    constexpr int MR   = BM / 32;
    constexpr int AL   = BM / 64;
    constexpr int ABUF = BM * 32;
    __shared__ u16 As[2 * ABUF];
    __shared__ u16 Bs[2 * 4096];
    const int tid  = threadIdx.x;
    const int lane = tid & 63;
    const int wid  = tid >> 6;
    const int wr   = wid >> 1, wc = wid & 1;

    const int rowBase = blockIdx.y * BM;
    const int colBase = blockIdx.x * 128;

    const int fr = lane & 15;
    const int hi = lane >> 4;

    const int sRowL  = lane >> 2;
    const int sChunk = lane & 3;
    const int aRow0 = wid * (BM / 4) + sRowL;
    const int aKey  = (aRow0 >> 1) & 3;
    const u16* aS0 = A + (size_t)(rowBase + aRow0) * lda + ((sChunk ^ aKey) << 3);
    const u16* aS1 = aS0 + (size_t)16 * lda;
    const int ldsA0 = (wid * (BM / 4)) * 32;
    const int ldsA1 = ldsA0 + 512;
    const int bRow0 = wid * 32 + sRowL;
    const int bKey  = (bRow0 >> 1) & 3;
    const u16* bS0 = Wt + (size_t)(colBase + bRow0) * K + ((sChunk ^ bKey) << 3);
    const u16* bS1 = bS0 + (size_t)16 * K;
    const int ldsB0 = (wid * 32) * 32;
    const int ldsB1 = ldsB0 + 512;

    const int swz = ((hi ^ ((fr >> 1) & 3)) << 3);
    const int aRd = (wr * (BM / 2) + fr) * 32 + swz;
    const int bRd = (wc * 64 + fr) * 32 + swz;

    f32x4 acc[MR][4] = {};
    const int nk = K >> 5;

    auto STAGE = [&](int kb, int buf) {
        u16* dA = As + buf * ABUF;
        u16* dB = Bs + buf * 4096;
        gload16(aS0 + kb, dA + ldsA0);
        if constexpr (AL == 2) gload16(aS1 + kb, dA + ldsA1);
        gload16(bS0 + kb, dB + ldsB0);
        gload16(bS1 + kb, dB + ldsB1);
    };

    STAGE(0, 0);
    __builtin_amdgcn_sched_barrier(0);
    STAGE(32, 1);
    __builtin_amdgcn_sched_barrier(0);
    if constexpr (BM == 128) asm volatile("s_waitcnt vmcnt(4)\n\ts_barrier" ::: "memory");
    else                     asm volatile("s_waitcnt vmcnt(3)\n\ts_barrier" ::: "memory");
    __builtin_amdgcn_sched_barrier(0);

    for (int t = 0; t < nk; ++t) {
        const int cur = t & 1;
        const u16* bA = As + cur * ABUF;
        const u16* bB = Bs + cur * 4096;
        bf8_t af[MR], bf[4];
        #pragma unroll
        for (int m = 0; m < MR; ++m)
            af[m] = *reinterpret_cast<const bf8_t*>(&bA[aRd + m * 512]);
        #pragma unroll
        for (int n = 0; n < 4; ++n)
            bf[n] = *reinterpret_cast<const bf8_t*>(&bB[bRd + n * 512]);
        #pragma unroll
        for (int m = 0; m < MR; ++m)
            #pragma unroll
            for (int n = 0; n < 4; ++n)
                acc[m][n] = __builtin_amdgcn_mfma_f32_16x16x32_bf16(af[m], bf[n], acc[m][n], 0, 0, 0);
        if (t == nk - 1) break;
        __builtin_amdgcn_sched_barrier(0);
        asm volatile("s_waitcnt lgkmcnt(0)\n\ts_barrier" ::: "memory");
        __builtin_amdgcn_sched_barrier(0);
        if (t + 2 < nk) {
            STAGE((t + 2) << 5, cur);
            __builtin_amdgcn_sched_barrier(0);
            if constexpr (BM == 128) asm volatile("s_waitcnt vmcnt(4)\n\ts_barrier" ::: "memory");
            else                     asm volatile("s_waitcnt vmcnt(3)\n\ts_barrier" ::: "memory");
        } else {
            asm volatile("s_waitcnt vmcnt(0)\n\ts_barrier" ::: "memory");
        }
        __builtin_amdgcn_sched_barrier(0);
    }

    const int orow = hi << 2;
    #pragma unroll
    for (int m = 0; m < MR; ++m) {
        int r0 = rowBase + wr * (BM / 2) + m * 16 + orow;
        #pragma unroll
        for (int n = 0; n < 4; ++n) {
            int c = colBase + wc * 64 + n * 16 + fr;
            float bv = bias ? bias[c] : 0.0f;
            #pragma unroll
            for (int r = 0; r < 4; ++r) {
                float v = acc[m][n][r] + bv;
                if (act == 1) v = gelu_exact(v);
                if (Cf)  Cf [(size_t)(r0 + r) * N + c] = v;
                if (Cb)  Cb [(size_t)(r0 + r) * ldcb  + c] = f2bf(v);
                if (Cb2) Cb2[(size_t)(r0 + r) * ldcb2 + c] = f2bf(v);
            }
        }
    }
}

// ---------------- logits GEMM: fp32 W streamed, reg-staged pipeline ----------------
__global__ __launch_bounds__(256) void gemm_logits(
    const float* __restrict__ A, int lda, const float* __restrict__ W,
    const float* __restrict__ bias, float* __restrict__ C, int N, int K)
{
    __shared__ u16 As[2][128][40];
    __shared__ u16 Bs[2][128][40];
    const int tid  = threadIdx.x;
    const int lane = tid & 63;
    const int wid  = tid >> 6;
    const int wr   = wid >> 1, wc = wid & 1;
    const int colBase = blockIdx.x * 128;

    const int a_r = tid >> 1;
    const int a_h = (tid & 1) << 4;
    const int b_c = tid & 127;
    const int b_h = (tid >> 7) << 4;

    const int fr = lane & 15;
    const int fk = (lane >> 4) << 3;

    f32x4 acc[4][4] = {};
    const int nvalid = N - colBase;
    const bool valid = b_c < nvalid;
    const int nk = K >> 5;

    float4 aR[4];
    float  bR[16];

    auto LD = [&](int kb) {
        const float* Ap = A + (size_t)a_r * lda + kb + a_h;
        #pragma unroll
        for (int q = 0; q < 4; ++q)
            aR[q] = *reinterpret_cast<const float4*>(Ap + q * 4);
        const float* Wp = W + (size_t)(kb + b_h) * N + colBase + b_c;
        #pragma unroll
        for (int kk = 0; kk < 16; ++kk)
            bR[kk] = valid ? Wp[(size_t)kk * N] : 0.0f;
    };
    auto ST = [&](int buf) {
        #pragma unroll
        for (int q = 0; q < 4; ++q) {
            ushort4 bb;
            bb.x = f2bf(aR[q].x); bb.y = f2bf(aR[q].y);
            bb.z = f2bf(aR[q].z); bb.w = f2bf(aR[q].w);
            *reinterpret_cast<ushort4*>(&As[buf][a_r][a_h + q * 4]) = bb;
        }
        u16 tmp[16];
        #pragma unroll
        for (int kk = 0; kk < 16; ++kk) tmp[kk] = f2bf(bR[kk]);
        *reinterpret_cast<bf8_t*>(&Bs[buf][b_c][b_h])     = *reinterpret_cast<const bf8_t*>(tmp);
        *reinterpret_cast<bf8_t*>(&Bs[buf][b_c][b_h + 8]) = *reinterpret_cast<const bf8_t*>(tmp + 8);
    };

    LD(0); ST(0);
    __syncthreads();

    for (int t = 0; t < nk; ++t) {
        if (t + 1 < nk) LD((t + 1) << 5);
        const int cur = t & 1;
        bf8_t af[4], bfv[4];
        #pragma unroll
        for (int m = 0; m < 4; ++m)
            af[m] = *reinterpret_cast<const bf8_t*>(&As[cur][wr * 64 + m * 16 + fr][fk]);
        #pragma unroll
        for (int n = 0; n < 4; ++n)
            bfv[n] = *reinterpret_cast<const bf8_t*>(&Bs[cur][wc * 64 + n * 16 + fr][fk]);
        #pragma unroll
        for (int m = 0; m < 4; ++m)
            #pragma unroll
            for (int n = 0; n < 4; ++n)
                acc[m][n] = __builtin_amdgcn_mfma_f32_16x16x32_bf16(af[m], bfv[n], acc[m][n], 0, 0, 0);
        if (t + 1 < nk) ST(cur ^ 1);
        __syncthreads();
    }

    const int orow = (lane >> 4) << 2;
    #pragma unroll
    for (int m = 0; m < 4; ++m) {
        int r0 = wr * 64 + m * 16 + orow;
        #pragma unroll
        for (int n = 0; n < 4; ++n) {
            int c = colBase + wc * 64 + n * 16 + fr;
            if (c < N) {
                float bv = bias ? bias[c] : 0.0f;
                #pragma unroll
                for (int r = 0; r < 4; ++r)
                    C[(size_t)(r0 + r) * N + c] = acc[m][n][r] + bv;
            }
        }
    }
}

// ---------------- self-attention (per (b,h) block) ----------------
__global__ __launch_bounds__(256) void attn_kernel(
    const u16* __restrict__ qkv, const float* __restrict__ rt, const int* __restrict__ rm,
    u16* __restrict__ ctxb)
{
    int bh = blockIdx.x;
    int b = bh >> 4, h = bh & 15;
    __shared__ float qs[S_][DK_ + 1], ks[S_][DK_ + 1], vs[S_][DK_ + 1];
    __shared__ float rts[5][DK_];
    __shared__ float Rs[S_][8];
    int tid = threadIdx.x;
    int wave = tid >> 6, lane = tid & 63;

    for (int idx = tid; idx < S_ * DK_; idx += 256) {
        int s = idx >> 6, d = idx & 63;
        size_t g = ((size_t)(b * S_ + s)) * (3 * D_) + h * DK_ + d;
        qs[s][d] = bf2f(qkv[g]);
        ks[s][d] = bf2f(qkv[g + D_]);
        vs[s][d] = bf2f(qkv[g + 2 * D_]);
    }
    for (int i = tid; i < 5 * DK_; i += 256)
        rts[i >> 6][i & 63] = rt[i];
    __syncthreads();

    for (int t = tid; t < S_ * 5; t += 256) {
        int i = t / 5, r = t - 5 * i;
        float a = 0.0f;
        #pragma unroll 8
        for (int d = 0; d < DK_; ++d) a += qs[i][d] * rts[r][d];
        Rs[i][r] = a;
    }
    __syncthreads();

    const float scale = 0.125f;
    for (int i = wave; i < S_; i += 4) {
        float sc = -INFINITY;
        if (lane < S_) {
            float acc = 0.0f;
            #pragma unroll 8
            for (int d = 0; d < DK_; ++d) acc += qs[i][d] * ks[lane][d];
            sc = acc * scale + 0.5f * Rs[i][rm[i * S_ + lane]];
        }
        float m = sc;
        #pragma unroll
        for (int off = 32; off; off >>= 1) m = fmaxf(m, __shfl_xor(m, off));
        float e = (lane < S_) ? expf(sc - m) : 0.0f;
        float sum = e;
        #pragma unroll
        for (int off = 32; off; off >>= 1) sum += __shfl_xor(sum, off);
        float aval = e / sum;

        float acc = 0.0f;
        for (int j = 0; j < S_; ++j) {
            float aj = __shfl(aval, j);
            acc += aj * vs[j][lane];
        }
        ctxb[((size_t)(b * S_ + i)) * D_ + h * DK_ + lane] = f2bf(acc);
    }
}

// ---------------- user embedding gather ----------------
__global__ __launch_bounds__(256) void gather_user(
    const float* __restrict__ ut, const int* __restrict__ ids,
    u16* __restrict__ o1, int ld1, u16* __restrict__ o2, int ld2)
{
    int b = blockIdx.x;
    int uid = ids[b];
    for (int d = threadIdx.x; d < D_; d += 256) {
        u16 v = f2bf(ut[(size_t)uid * D_ + d]);
        o1[(size_t)b * ld1 + d] = v;
        o2[(size_t)b * ld2 + d] = v;
    }
}

// ---------------- cross attention (q_len = 1); K/V merged [BS][2048] ----------------
__global__ __launch_bounds__(64) void cross_attn(
    const u16* __restrict__ qh, const u16* __restrict__ kv, u16* __restrict__ up)
{
    int bh = blockIdx.x;
    int b = bh >> 4, h = bh & 15;
    int lane = threadIdx.x;
    __shared__ float qv[DK_];
    qv[lane] = bf2f(qh[(size_t)b * D_ + h * DK_ + lane]);
    __syncthreads();
    float sc = -INFINITY;
    if (lane < S_) {
        float acc = 0.0f;
        const u16* krow = kv + ((size_t)(b * S_ + lane)) * 2048 + h * DK_;
        #pragma unroll 8
        for (int d = 0; d < DK_; ++d) acc += qv[d] * bf2f(krow[d]);
        sc = acc * 0.125f;
    }
    float m = sc;
    #pragma unroll
    for (int off = 32; off; off >>= 1) m = fmaxf(m, __shfl_xor(m, off));
    float e = (lane < S_) ? expf(sc - m) : 0.0f;
    float sum = e;
    #pragma unroll
    for (int off = 32; off; off >>= 1) sum += __shfl_xor(sum, off);
    float aval = e / sum;
    float acc = 0.0f;
    for (int j = 0; j < S_; ++j) {
        float aj = __shfl(aval, j);
        acc += aj * bf2f(kv[((size_t)(b * S_ + j)) * 2048 + 1024 + h * DK_ + lane]);
    }
    up[(size_t)b * D_ + h * DK_ + lane] = f2bf(acc);
}

// ---------------- sequence mean ----------------
__global__ __launch_bounds__(256) void seq_mean(
    const float* __restrict__ x,
    u16* __restrict__ o1, int ld1, u16* __restrict__ o2, int ld2)
{
    int b = blockIdx.x;
    for (int d = threadIdx.x; d < D_; d += 256) {
        float s = 0.0f;
        for (int si = 0; si < S_; ++si)
            s += x[((size_t)(b * S_ + si)) * D_ + d];
        u16 v = f2bf(s * (1.0f / S_));
        o1[(size_t)b * ld1 + d] = v;
        o2[(size_t)b * ld2 + d] = v;
    }
}

// ---------------- fused final heads ----------------
__global__ __launch_bounds__(256) void heads_final(
    const float* __restrict__ h1cn, const float* __restrict__ h1r, const float* __restrict__ ho,
    const float* __restrict__ c_w2, const float* __restrict__ c_b2,
    const float* __restrict__ r_w2, const float* __restrict__ r_b2,
    const float* __restrict__ o_w2, const float* __restrict__ o_b2,
    float* __restrict__ comp, float* __restrict__ rating, float* __restrict__ order)
{
    int b = blockIdx.x;
    int lane = threadIdx.x & 63, wv = threadIdx.x >> 6;
    if (wv == 0) {
        float s = 0.0f;
        for (int d = lane; d < D_; d += 64) s += h1cn[(size_t)b * 2048 + d] * c_w2[d];
        #pragma unroll
        for (int off = 32; off; off >>= 1) s += __shfl_xor(s, off);
        if (lane == 0) comp[b] = 1.0f / (1.0f + expf(-(s + c_b2[0])));
    } else if (wv == 1) {
        float s = 0.0f;
        for (int d = lane; d < D_; d += 64) s += h1r[(size_t)b * D_ + d] * r_w2[d];
        #pragma unroll
        for (int off = 32; off; off >>= 1) s += __shfl_xor(s, off);
        if (lane == 0) rating[b] = s + r_b2[0];
    } else if (wv == 2) {
        float s0 = 0.0f, s1 = 0.0f;
        for (int d = lane; d < 512; d += 64) {
            float hv = ho[(size_t)b * 512 + d];
            s0 += hv * o_w2[d * 2];
            s1 += hv * o_w2[d * 2 + 1];
        }
        #pragma unroll
        for (int off = 32; off; off >>= 1) { s0 += __shfl_xor(s0, off); s1 += __shfl_xor(s1, off); }
        if (lane == 0) {
            float a = s0 + o_b2[0], c = s1 + o_b2[1];
            float m = fmaxf(a, c);
            float ea = expf(a - m), ec = expf(c - m);
            float s = ea + ec;
            order[b * 2] = ea / s;
            order[b * 2 + 1] = ec / s;
        }
    }
}

// ---------------- host-side launcher ----------------
extern "C" void kernel_launch(void* const* d_in, const int* in_sizes, int n_in,
                              void* d_out, int out_size, void* d_ws, size_t ws_size,
                              hipStream_t stream) {
    const float* movie_table = (const float*)d_in[0];
    const float* fran_table  = (const float*)d_in[1];
    const float* entry_table = (const float*)d_in[2];
    const float* proj_w      = (const float*)d_in[3];
    const float* proj_b      = (const float*)d_in[4];
    const float* wq          = (const float*)d_in[5];
    const float* bq          = (const float*)d_in[6];
    const float* wk          = (const float*)d_in[7];
    const float* bk          = (const float*)d_in[8];
    const float* wv          = (const float*)d_in[9];
    const float* bv          = (const float*)d_in[10];
    const float* wo          = (const float*)d_in[11];
    const float* bo          = (const float*)d_in[12];
    const float* rel_table   = (const float*)d_in[13];
    const float* aln_g       = (const float*)d_in[14];
    const float* aln_b       = (const float*)d_in[15];
    const float* f_w1        = (const float*)d_in[16];
    const float* f_b1        = (const float*)d_in[17];
    const float* f_w2        = (const float*)d_in[18];
    const float* f_b2        = (const float*)d_in[19];
    const float* ln_g        = (const float*)d_in[20];
    const float* ln_b        = (const float*)d_in[21];
    const float* user_table  = (const float*)d_in[22];
    const float* mq_w        = (const float*)d_in[23];
    const float* mq_b        = (const float*)d_in[24];
    const float* mk_w        = (const float*)d_in[25];
    const float* mk_b        = (const float*)d_in[26];
    const float* mv_w        = (const float*)d_in[27];
    const float* mv_b        = (const float*)d_in[28];
    const float* mo_w        = (const float*)d_in[29];
    const float* mo_b        = (const float*)d_in[30];
    const float* c_w1        = (const float*)d_in[31];
    const float* c_b1        = (const float*)d_in[32];
    const float* c_w2        = (const float*)d_in[33];
    const float* c_b2        = (const float*)d_in[34];
    const float* n_w1        = (const float*)d_in[35];
    const float* n_b1        = (const float*)d_in[36];
    const float* n_w2        = (const float*)d_in[37];
    const float* n_b2        = (const float*)d_in[38];
    const float* r_w1        = (const float*)d_in[39];
    const float* r_b1        = (const float*)d_in[40];
    const float* r_w2        = (const float*)d_in[41];
    const float* r_b2        = (const float*)d_in[42];
    const float* o_w1        = (const float*)d_in[43];
    const float* o_b1        = (const float*)d_in[44];
    const float* o_w2        = (const float*)d_in[45];
    const float* o_b2        = (const float*)d_in[46];
    const int* user_ids      = (const int*)d_in[47];
    const int* movie_ids     = (const int*)d_in[48];
    const int* franchise_ids = (const int*)d_in[49];
    const int* entry_types   = (const int*)d_in[50];
    const int* relation_mat  = (const int*)d_in[51];

    // ---- workspace layout (u16 units) ----
    u16* up16 = (u16*)d_ws;
    u16* proj_wt = up16;                                   // [1024][1536]
    u16* wqkv_t  = proj_wt + (size_t)1024 * 1536;          // [4][3072][1024]
    u16* wo_t    = wqkv_t  + (size_t)4 * 3072 * 1024;      // [4][1024][1024]
    u16* fw1_buf = wo_t    + (size_t)4 * 1024 * 1024;      // [4096][1024]
    u16* fw2_buf = fw1_buf + (size_t)4096 * 1024;          // [1024][4096]
    u16* mq_t    = fw2_buf + (size_t)1024 * 4096;          // [1024][1024]
    u16* mk_t    = mq_t    + (size_t)1024 * 1024;          // mk|mv = [2048][1024]
    u16* mv_t    = mk_t    + (size_t)1024 * 1024;
    u16* mo_t    = mv_t    + (size_t)1024 * 1024;
    u16* cn_w1t  = mo_t    + (size_t)1024 * 1024;          // [2048][2048]
    u16* r_w1t   = cn_w1t  + (size_t)2048 * 2048;          // [1024][3072]
    u16* o_w1t   = r_w1t   + (size_t)1024 * 3072;          // [512][1024]
    u16* ffb     = o_w1t   + (size_t)512 * 1024;           // [6400][4096]
    u16* xinb    = ffb;                                    // [6400][1536] (dead after proj)
    u16* xb      = ffb     + (size_t)BS_ * FF_;            // [6400][1024]
    u16* xb2     = xb      + (size_t)BS_ * D_;             // [6400][1024]
    u16* qkvb    = xb2     + (size_t)BS_ * D_;             // [6400][3072]
    u16* kvb     = qkvb    + (size_t)BS_ * 3 * D_;         // [6400][2048]
    u16* ctxb    = kvb;
    u16* ueb     = kvb     + (size_t)BS_ * 2 * D_;         // [128][1024]
    u16* upb_pre = ueb     + (size_t)B_ * D_;              // [128][1024]
    u16* cib     = upb_pre + (size_t)B_ * D_;              // [128][2048]
    u16* rib     = cib     + (size_t)B_ * 2 * D_;          // [128][3072]
    float* fp    = (float*)(rib + (size_t)B_ * 3 * D_);
    float* bqkv  = fp;                                     // [4][3072]
    float* bcn   = bqkv + 4 * 3072;                        // [2048]
    float* bkv   = bcn  + 2048;                            // [2048]
    float* pet   = bkv  + 2048;                            // [50][1024]
    float* h1cn  = pet  + 50 * 1024;                       // [128][2048]
    float* h1r   = h1cn + (size_t)B_ * 2048;               // [128][1024]
    float* ho    = h1r  + (size_t)B_ * D_;                 // [128][512]

    // split-K partial buffers (bf16) aliased over dead regions ([6400][1024] u16 each)
    u16* pQK = qkvb;   // dead after attn / before QKV
    u16* pKV = kvb;    // dead except when ctx/mkmv live
    u16* pFF = ffb;    // dead before FF1 of the layer

    // ---- d_out layout ----
    float* xout    = (float*)d_out;                 // [BS, D]
    float* comp    = xout + (size_t)BS_ * D_;       // [B,1]
    float* logits  = comp + B_;                     // [B,V]
    float* rating  = logits + (size_t)B_ * V_;      // [B,1]
    float* order   = rating + B_;                   // [B,2]
    float* upref   = order + 2 * B_;                // [B,D]

    dim3 blk(256);

    // ---- weight conversion pass ----
    wtrans<<<dim3(32, 48, 1), blk, 0, stream>>>(proj_w, proj_wt, 1536, 1024, 0, 0, 0);
    wtrans_qkv<<<dim3(32, 32, 12), blk, 0, stream>>>(wq, wk, wv, wqkv_t);
    WT8 w8;
    w8.s[0] = wo;                 w8.d[0] = wo_t;
    w8.s[1] = wo + 1048576;       w8.d[1] = wo_t + 1048576;
    w8.s[2] = wo + 2097152;       w8.d[2] = wo_t + 2097152;
    w8.s[3] = wo + 3145728;       w8.d[3] = wo_t + 3145728;
    w8.s[4] = mq_w;               w8.d[4] = mq_t;
    w8.s[5] = mk_w;               w8.d[5] = mk_t;
    w8.s[6] = mv_w;               w8.d[6] = mv_t;
    w8.s[7] = mo_w;               w8.d[7] = mo_t;
    wtrans8<<<dim3(32, 32, 8), blk, 0, stream>>>(w8);
    wtrans<<<dim3(32, 64, 1), blk, 0, stream>>>(c_w1, cn_w1t, 2048, 1024, 0, 0, 0);
    wtrans<<<dim3(32, 64, 1), blk, 0, stream>>>(n_w1, cn_w1t, 2048, 1024, 0, 0, 1024);
    wtrans<<<dim3(32, 96, 1), blk, 0, stream>>>(r_w1, r_w1t, 3072, 1024, 0, 0, 0);
    wtrans<<<dim3(16, 32, 1), blk, 0, stream>>>(o_w1, o_w1t, 1024, 512, 0, 0, 0);
    setup_misc<<<dim3(56), blk, 0, stream>>>(bq, bk, bv, c_b1, n_b1, mk_b, mv_b,
                                             bqkv, bcn, bkv, pet);

    // ---- encoder input: proj split-K (bf16 partials over qkvb/kvb) + combine ----
    embed_concat<<<BS_, blk, 0, stream>>>(movie_table, fran_table, entry_table,
                                          movie_ids, franchise_ids, entry_types, xinb);
    gemm_sk32<<<dim3(8, 50, 2), blk, 0, stream>>>(xinb, 1536, proj_wt, 1536,
                                                  pQK, pKV, D_, 768);
    combine_bias_pe<<<BS_, blk, 0, stream>>>(pQK, pKV, proj_b, pet, xb);

    // ---- transformer layers (x ping-pong: xb -> xb2 -> xb) ----
    for (int l = 0; l < L_; ++l) {
        gemm128_w32<<<dim3(24, 50), blk, 0, stream>>>(xb, 1024,
                wqkv_t + (size_t)l * 3145728, bqkv + l * 3072,
                qkvb, 3072, 3 * D_, D_, 0);
        attn_kernel<<<B_ * H_, blk, 0, stream>>>(qkvb, rel_table + (size_t)l * 5 * DK_,
                                                 relation_mat, ctxb);
        // WO split-K: partials over qkvb (dead) + ffb (dead until FF1)
        gemm_sk32<<<dim3(8, 50, 2), blk, 0, stream>>>(ctxb, 1024,
                wo_t + (size_t)l * 1048576, 1024, pQK, pFF, D_, 512);
        add_ln2<<<BS_, blk, 0, stream>>>(pQK, pFF, bo + l * D_, xb,
                                         aln_g + l * D_, aln_b + l * D_, xb2, nullptr);
        wtrans_ff<<<dim3(128, 32, 2), blk, 0, stream>>>(f_w1 + (size_t)l * D_ * FF_,
                                                        f_w2 + (size_t)l * FF_ * D_,
                                                        fw1_buf, fw2_buf);
        gemm128_w32<<<dim3(32, 50), blk, 0, stream>>>(xb2, 1024, fw1_buf, f_b1 + l * FF_,
                ffb, 4096, FF_, D_, 1);
        // FF2 split-K: partials over qkvb + kvb (both dead here)
        gemm_sk32<<<dim3(8, 50, 2), blk, 0, stream>>>(ffb, 4096, fw2_buf, 4096,
                                                      pQK, pKV, D_, 2048);
        add_ln2<<<BS_, blk, 0, stream>>>(pQK, pKV, f_b2 + l * D_, xb2,
                                         ln_g + l * D_, ln_b + l * D_, xb,
                                         (l == L_ - 1) ? xout : nullptr);
    }

    // ---- user cross-attention ----
    gather_user<<<B_, blk, 0, stream>>>(user_table, user_ids, ueb, 1024, rib, 3072);
    gemm_bf16_t<64><<<dim3(8, 2), blk, 0, stream>>>(ueb, 1024, mq_t, mq_b,
            nullptr, qkvb, 1024, nullptr, 0, D_, D_, 0);
    gemm128_w32<<<dim3(16, 50), blk, 0, stream>>>(xb, 1024, mk_t, bkv,
            kvb, 2048, 2 * D_, D_, 0);
    cross_attn<<<B_ * H_, dim3(64), 0, stream>>>(qkvb, kvb, upb_pre);
    gemm_bf16_t<64><<<dim3(8, 2), blk, 0, stream>>>(upb_pre, 1024, mo_t, mo_b,
            upref, cib, 2048, rib + 1024, 3072, D_, D_, 0);

    // ---- sequence mean (writes into both concats) ----
    seq_mean<<<B_, blk, 0, stream>>>(xout, cib + 1024, 2048, rib + 2048, 3072);

    // ---- heads ----
    gemm_bf16_t<64><<<dim3(16, 2), blk, 0, stream>>>(cib, 2048, cn_w1t, bcn,
            h1cn, nullptr, 0, nullptr, 0, 2048, 2048, 1);
    gemm_bf16_t<64><<<dim3(8, 2), blk, 0, stream>>>(rib, 3072, r_w1t, r_b1,
            h1r, nullptr, 0, nullptr, 0, D_, 3072, 1);
    gemm_bf16_t<64><<<dim3(4, 2), blk, 0, stream>>>(cib, 2048, o_w1t, o_b1,
            ho, nullptr, 0, nullptr, 0, 512, D_, 1);
    gemm_logits<<<dim3(782, 1), blk, 0, stream>>>(h1cn + 1024, 2048, n_w2, n_b2,
                                                  logits, V_, D_);
    heads_final<<<B_, blk, 0, stream>>>(h1cn, h1r, ho, c_w2, c_b2, r_w2, r_b2,
                                        o_w2, o_b2, comp, rating, order);
}

// Round 12
// 2108.492 us; speedup vs baseline: 1.1188x; 1.0101x over previous
//
#include <hip/hip_runtime.h>
#include <hip/hip_bf16.h>
#include <math.h>

// ---------------- problem constants ----------------
#define B_   128
#define S_   50
#define BS_  (B_*S_)        // 6400
#define E_   512
#define D_   1024
#define H_   16
#define DK_  64
#define L_   4
#define FF_  4096
#define V_   100000

typedef short bf8_t __attribute__((ext_vector_type(8)));
typedef float f32x4 __attribute__((ext_vector_type(4)));
typedef float f32x16 __attribute__((ext_vector_type(16)));
typedef unsigned short u16;

__device__ __forceinline__ float gelu_exact(float x) {
    return 0.5f * x * (1.0f + erff(x * 0.70710678118654752440f));
}
__device__ __forceinline__ u16 f2bf(float f) {
    unsigned int u = __float_as_uint(f);
    return (u16)((u + 0x7FFFu + ((u >> 16) & 1u)) >> 16);
}
__device__ __forceinline__ float bf2f(u16 u) {
    return __uint_as_float(((unsigned int)u) << 16);
}

// async global->LDS, 16B per lane
__device__ __forceinline__ void gload16(const u16* g, u16* l) {
    auto* g1 = reinterpret_cast<const __attribute__((address_space(1))) unsigned int*>(
                   reinterpret_cast<uintptr_t>(g));
    auto* l3 = reinterpret_cast<__attribute__((address_space(3))) unsigned int*>(
                   reinterpret_cast<uintptr_t>(l));
    __builtin_amdgcn_global_load_lds(g1, l3, 16, 0, 0);
}

// ---------------- weight transpose bodies ----------------
__device__ __forceinline__ void wtrans_body(
    const float* __restrict__ W, u16* __restrict__ Wt,
    int K, int N, int nb, int kb, int dstRowOff)
{
    __shared__ float t[32][33];
    int c = threadIdx.x & 31, r0 = threadIdx.x >> 5;
    #pragma unroll
    for (int rr = 0; rr < 32; rr += 8)
        t[rr + r0][c] = W[(size_t)(kb + rr + r0) * N + nb + c];
    __syncthreads();
    #pragma unroll
    for (int rr = 0; rr < 32; rr += 8)
        Wt[(size_t)(dstRowOff + nb + rr + r0) * K + kb + c] = f2bf(t[c][rr + r0]);
}

__global__ __launch_bounds__(256) void wtrans(
    const float* __restrict__ W, u16* __restrict__ Wt,
    int K, int N, long srcLS, long dstLS, int dstRowOff)
{
    int l = blockIdx.z;
    wtrans_body(W + (size_t)l * srcLS, Wt + (size_t)l * dstLS,
                K, N, blockIdx.x * 32, blockIdx.y * 32, dstRowOff);
}

__global__ __launch_bounds__(256) void wtrans_qkv(
    const float* __restrict__ wq, const float* __restrict__ wk, const float* __restrict__ wv,
    u16* __restrict__ dst)
{
    int z = blockIdx.z;
    int l = z & 3, which = z >> 2;
    const float* W = (which == 0 ? wq : which == 1 ? wk : wv) + (size_t)l * (D_ * D_);
    u16* Wt = dst + (size_t)l * (3 * D_ * D_) + (size_t)which * (D_ * D_);
    wtrans_body(W, Wt, D_, D_, blockIdx.x * 32, blockIdx.y * 32, 0);
}

struct WT8 { const float* s[8]; u16* d[8]; };
__global__ __launch_bounds__(256) void wtrans8(WT8 p)
{
    int z = blockIdx.z;
    wtrans_body(p.s[z], p.d[z], D_, D_, blockIdx.x * 32, blockIdx.y * 32, 0);
}

__global__ __launch_bounds__(256) void wtrans_ff(
    const float* __restrict__ w1, const float* __restrict__ w2,
    u16* __restrict__ d1, u16* __restrict__ d2)
{
    if (blockIdx.z == 0)
        wtrans_body(w1, d1, D_, FF_, blockIdx.x * 32, blockIdx.y * 32, 0);
    else
        wtrans_body(w2, d2, FF_, D_, blockIdx.y * 32, blockIdx.x * 32, 0);
}

// ---------------- embedding gather + concat (bf16 out) ----------------
__global__ __launch_bounds__(256) void embed_concat(
    const float* __restrict__ mt, const float* __restrict__ ft, const float* __restrict__ et,
    const int* __restrict__ mids, const int* __restrict__ fids, const int* __restrict__ eids,
    u16* __restrict__ xinb)
{
    int bs = blockIdx.x;
    int mid = mids[bs], fid = fids[bs], eid = eids[bs];
    const float* srcs[3] = { mt + (size_t)mid * E_, ft + (size_t)fid * E_, et + (size_t)eid * E_ };
    u16* dst = xinb + (size_t)bs * (3 * E_);
    for (int i = threadIdx.x; i < 384; i += 256) {
        int seg = i >> 7, off = i & 127;
        float4 v = reinterpret_cast<const float4*>(srcs[seg])[off];
        ushort4 b;
        b.x = f2bf(v.x); b.y = f2bf(v.y); b.z = f2bf(v.z); b.w = f2bf(v.w);
        reinterpret_cast<ushort4*>(dst + seg * E_)[off] = b;
    }
}

// ---------------- setup misc: bias concats + PE table ----------------
__global__ __launch_bounds__(256) void setup_misc(
    const float* __restrict__ bq, const float* __restrict__ bk, const float* __restrict__ bv,
    const float* __restrict__ cb1, const float* __restrict__ nb1,
    const float* __restrict__ mkb, const float* __restrict__ mvb,
    float* __restrict__ bqkv, float* __restrict__ bcn, float* __restrict__ bkv,
    float* __restrict__ pet)
{
    int bi = blockIdx.x, tid = threadIdx.x;
    if (bi < 4) {
        for (int c = tid; c < 3072; c += 256) {
            float v = (c < 1024) ? bq[bi * 1024 + c]
                    : (c < 2048) ? bk[bi * 1024 + c - 1024]
                                 : bv[bi * 1024 + c - 2048];
            bqkv[bi * 3072 + c] = v;
        }
    } else if (bi == 4) {
        for (int c = tid; c < 2048; c += 256)
            bcn[c] = (c < 1024) ? cb1[c] : nb1[c - 1024];
    } else if (bi == 5) {
        for (int c = tid; c < 2048; c += 256)
            bkv[c] = (c < 1024) ? mkb[c] : mvb[c - 1024];
    } else {
        int s = bi - 6;
        const float cc = -logf(10000.0f) / 512.0f;
        for (int d = tid; d < D_; d += 256) {
            int second = d >= 512;
            int c2 = second ? d - 512 : d;
            int i = c2 >> 1;
            float div = expf(cc * (float)(2 * i));
            float aa = (float)s * div * (second ? 1.5f : 1.0f);
            pet[s * D_ + d] = (c2 & 1) ? cosf(aa) : sinf(aa);
        }
    }
}

// ---------------- 128x128 / 4-wave GEMM, 32x32x16 MFMA, depth-3 single-barrier ----------------
// A bf16 [M,lda], Wt bf16 [N,K] row-major, bias fp32[N]. M%128==0, N%128==0, K%32==0, nk>=2.
// grid (N/128, M/128). Per K-step: ONE combined "vmcnt(4) lgkmcnt(0); s_barrier".
// 3 LDS buffers rotate; stage(t+2) issued inside iter t; loads never drained to 0 until tail.
__global__ __launch_bounds__(256) void gemm128_w32(
    const u16* __restrict__ A, int lda, const u16* __restrict__ Wt,
    const float* __restrict__ bias,
    u16* __restrict__ Cb, int ldcb,
    int N, int K, int act)
{
    __shared__ u16 As[3 * 4096];
    __shared__ u16 Bs[3 * 4096];
    const int tid  = threadIdx.x;
    const int lane = tid & 63;
    const int wid  = tid >> 6;
    const int wr   = wid >> 1, wc = wid & 1;

    // XCD-bijective swizzle (m204)
    const int gx  = gridDim.x;
    const int nwg = gx * gridDim.y;
    int orig = blockIdx.y * gx + blockIdx.x;
    int qq = nwg >> 3, rr2 = nwg & 7, xcd = orig & 7, idx = orig >> 3;
    int wgid = (xcd < rr2) ? (xcd * (qq + 1) + idx)
                           : (rr2 * (qq + 1) + (xcd - rr2) * qq + idx);
    const int rowBase = (wgid / gx) * 128;
    const int colBase = (wgid % gx) * 128;

    // staging geometry
    const int sRowL  = lane >> 2;
    const int sChunk = lane & 3;
    const int gRow0  = (wid << 5) + sRowL;
    const int skey   = (gRow0 >> 1) & 3;           // same for gRow0+16
    const int gC     = (sChunk ^ skey) << 3;
    const u16* aS0 = A  + (size_t)(rowBase + gRow0) * lda + gC;
    const u16* aS1 = aS0 + (size_t)16 * lda;
    const u16* bS0 = Wt + (size_t)(colBase + gRow0) * K + gC;
    const u16* bS1 = bS0 + (size_t)16 * K;
    const int ldsW0 = (wid << 5) << 5;
    const int ldsW1 = ldsW0 + (16 << 5);

    // 32x32x16 fragment geometry
    const int l31 = lane & 31;
    const int hi5 = lane >> 5;
    const int key32 = (l31 >> 1) & 3;
    const int c0 = (0 | hi5) ^ key32;
    const int c1 = (2 | hi5) ^ key32;
    const int aB0 = (wr * 64 + l31) * 32;
    const int bB0 = (wc * 64 + l31) * 32;

    f32x16 acc[2][2] = {};
    const int nk = K >> 5;

    auto STAGE = [&](int kb, int buf) {
        u16* dA = As + buf * 4096;
        u16* dB = Bs + buf * 4096;
        gload16(aS0 + kb, dA + ldsW0);
        gload16(aS1 + kb, dA + ldsW1);
        gload16(bS0 + kb, dB + ldsW0);
        gload16(bS1 + kb, dB + ldsW1);
    };

    STAGE(0, 0);
    __builtin_amdgcn_sched_barrier(0);
    STAGE(32, 1);
    __builtin_amdgcn_sched_barrier(0);

    int cur = 0;
    for (int t = 0; t < nk; ++t) {
        if (t < nk - 1) asm volatile("s_waitcnt vmcnt(4) lgkmcnt(0)\n\ts_barrier" ::: "memory");
        else            asm volatile("s_waitcnt vmcnt(0) lgkmcnt(0)\n\ts_barrier" ::: "memory");
        __builtin_amdgcn_sched_barrier(0);
        const u16* bA = As + cur * 4096;
        const u16* bB = Bs + cur * 4096;
        bf8_t aF[2][2], bF[2][2];
        #pragma unroll
        for (int mi = 0; mi < 2; ++mi) {
            aF[mi][0] = *reinterpret_cast<const bf8_t*>(&bA[aB0 + mi * 1024 + c0 * 8]);
            aF[mi][1] = *reinterpret_cast<const bf8_t*>(&bA[aB0 + mi * 1024 + c1 * 8]);
        }
        #pragma unroll
        for (int ni = 0; ni < 2; ++ni) {
            bF[ni][0] = *reinterpret_cast<const bf8_t*>(&bB[bB0 + ni * 1024 + c0 * 8]);
            bF[ni][1] = *reinterpret_cast<const bf8_t*>(&bB[bB0 + ni * 1024 + c1 * 8]);
        }
        if (t + 2 < nk) {
            int nb = cur + 2; if (nb >= 3) nb -= 3;
            STAGE((t + 2) << 5, nb);
        }
        __builtin_amdgcn_sched_barrier(0);
        #pragma unroll
        for (int mi = 0; mi < 2; ++mi)
            #pragma unroll
            for (int ni = 0; ni < 2; ++ni) {
                acc[mi][ni] = __builtin_amdgcn_mfma_f32_32x32x16_bf16(aF[mi][0], bF[ni][0], acc[mi][ni], 0, 0, 0);
                acc[mi][ni] = __builtin_amdgcn_mfma_f32_32x32x16_bf16(aF[mi][1], bF[ni][1], acc[mi][ni], 0, 0, 0);
            }
        cur = (cur == 2) ? 0 : cur + 1;
    }

    // epilogue: 32x32 C/D map col=lane&31, row=(reg&3)+8*(reg>>2)+4*(lane>>5)
    #pragma unroll
    for (int mi = 0; mi < 2; ++mi) {
        int rt = rowBase + wr * 64 + mi * 32 + 4 * hi5;
        #pragma unroll
        for (int ni = 0; ni < 2; ++ni) {
            int ct = colBase + wc * 64 + ni * 32 + l31;
            float bv = bias ? bias[ct] : 0.0f;
            #pragma unroll
            for (int r = 0; r < 16; ++r) {
                int rr = rt + (r & 3) + 8 * (r >> 2);
                float v = acc[mi][ni][r] + bv;
                if (act == 1) v = gelu_exact(v);
                Cb[(size_t)rr * ldcb + ct] = f2bf(v);
            }
        }
    }
}

// ---------------- split-K GEMM: bf16 partials, 32x32 MFMA, depth-3 single-barrier ----------------
__global__ __launch_bounds__(256) void gemm_sk32(
    const u16* __restrict__ A, int lda, const u16* __restrict__ Wt, int ldb,
    u16* __restrict__ P0, u16* __restrict__ P1,
    int N, int Kh)
{
    __shared__ u16 As[3 * 4096];
    __shared__ u16 Bs[3 * 4096];
    const int tid  = threadIdx.x;
    const int lane = tid & 63;
    const int wid  = tid >> 6;
    const int wr   = wid >> 1, wc = wid & 1;

    const int gx  = gridDim.x;
    const int nwg = gx * gridDim.y;
    int orig = blockIdx.y * gx + blockIdx.x;
    int qq = nwg >> 3, rr2 = nwg & 7, xcd = orig & 7, idx = orig >> 3;
    int wgid = (xcd < rr2) ? (xcd * (qq + 1) + idx)
                           : (rr2 * (qq + 1) + (xcd - rr2) * qq + idx);
    const int rowBase = (wgid / gx) * 128;
    const int colBase = (wgid % gx) * 128;
    const int k0 = blockIdx.z * Kh;
    u16* P = blockIdx.z ? P1 : P0;

    const int sRowL  = lane >> 2;
    const int sChunk = lane & 3;
    const int gRow0  = (wid << 5) + sRowL;
    const int skey   = (gRow0 >> 1) & 3;
    const int gC     = (sChunk ^ skey) << 3;
    const u16* aS0 = A  + (size_t)(rowBase + gRow0) * lda + k0 + gC;
    const u16* aS1 = aS0 + (size_t)16 * lda;
    const u16* bS0 = Wt + (size_t)(colBase + gRow0) * ldb + k0 + gC;
    const u16* bS1 = bS0 + (size_t)16 * ldb;
    const int ldsW0 = (wid << 5) << 5;
    const int ldsW1 = ldsW0 + (16 << 5);

    const int l31 = lane & 31;
    const int hi5 = lane >> 5;
    const int key32 = (l31 >> 1) & 3;
    const int c0 = (0 | hi5) ^ key32;
    const int c1 = (2 | hi5) ^ key32;
    const int aB0 = (wr * 64 + l31) * 32;
    const int bB0 = (wc * 64 + l31) * 32;

    f32x16 acc[2][2] = {};
    const int nk = Kh >> 5;

    auto STAGE = [&](int kb, int buf) {
        u16* dA = As + buf * 4096;
        u16* dB = Bs + buf * 4096;
        gload16(aS0 + kb, dA + ldsW0);
        gload16(aS1 + kb, dA + ldsW1);
        gload16(bS0 + kb, dB + ldsW0);
        gload16(bS1 + kb, dB + ldsW1);
    };

    STAGE(0, 0);
    __builtin_amdgcn_sched_barrier(0);
    STAGE(32, 1);
    __builtin_amdgcn_sched_barrier(0);

    int cur = 0;
    for (int t = 0; t < nk; ++t) {
        if (t < nk - 1) asm volatile("s_waitcnt vmcnt(4) lgkmcnt(0)\n\ts_barrier" ::: "memory");
        else            asm volatile("s_waitcnt vmcnt(0) lgkmcnt(0)\n\ts_barrier" ::: "memory");
        __builtin_amdgcn_sched_barrier(0);
        const u16* bA = As + cur * 4096;
        const u16* bB = Bs + cur * 4096;
        bf8_t aF[2][2], bF[2][2];
        #pragma unroll
        for (int mi = 0; mi < 2; ++mi) {
            aF[mi][0] = *reinterpret_cast<const bf8_t*>(&bA[aB0 + mi * 1024 + c0 * 8]);
            aF[mi][1] = *reinterpret_cast<const bf8_t*>(&bA[aB0 + mi * 1024 + c1 * 8]);
        }
        #pragma unroll
        for (int ni = 0; ni < 2; ++ni) {
            bF[ni][0] = *reinterpret_cast<const bf8_t*>(&bB[bB0 + ni * 1024 + c0 * 8]);
            bF[ni][1] = *reinterpret_cast<const bf8_t*>(&bB[bB0 + ni * 1024 + c1 * 8]);
        }
        if (t + 2 < nk) {
            int nb = cur + 2; if (nb >= 3) nb -= 3;
            STAGE((t + 2) << 5, nb);
        }
        __builtin_amdgcn_sched_barrier(0);
        #pragma unroll
        for (int mi = 0; mi < 2; ++mi)
            #pragma unroll
            for (int ni = 0; ni < 2; ++ni) {
                acc[mi][ni] = __builtin_amdgcn_mfma_f32_32x32x16_bf16(aF[mi][0], bF[ni][0], acc[mi][ni], 0, 0, 0);
                acc[mi][ni] = __builtin_amdgcn_mfma_f32_32x32x16_bf16(aF[mi][1], bF[ni][1], acc[mi][ni], 0, 0, 0);
            }
        cur = (cur == 2) ? 0 : cur + 1;
    }

    #pragma unroll
    for (int mi = 0; mi < 2; ++mi) {
        int rt = rowBase + wr * 64 + mi * 32 + 4 * hi5;
        #pragma unroll
        for (int ni = 0; ni < 2; ++ni) {
            int ct = colBase + wc * 64 + ni * 32 + l31;
            #pragma unroll
            for (int r = 0; r < 16; ++r) {
                int rr = rt + (r & 3) + 8 * (r >> 2);
                P[(size_t)rr * N + ct] = f2bf(acc[mi][ni][r]);
            }
        }
    }
}

// ---------------- combine: xb = bf16(p1 + p2 + bias + pe) ----------------
__global__ __launch_bounds__(256) void combine_bias_pe(
    const u16* __restrict__ p1, const u16* __restrict__ p2,
    const float* __restrict__ bias, const float* __restrict__ pe,
    u16* __restrict__ outb)
{
    int row = blockIdx.x, tid = threadIdx.x;
    int c0 = tid << 2;
    size_t base = (size_t)row * D_ + c0;
    ushort4 v1 = *reinterpret_cast<const ushort4*>(p1 + base);
    ushort4 v2 = *reinterpret_cast<const ushort4*>(p2 + base);
    float4 bv = *reinterpret_cast<const float4*>(bias + c0);
    float4 pv = *reinterpret_cast<const float4*>(pe + (size_t)(row % S_) * D_ + c0);
    ushort4 ob;
    ob.x = f2bf(bf2f(v1.x) + bf2f(v2.x) + bv.x + pv.x);
    ob.y = f2bf(bf2f(v1.y) + bf2f(v2.y) + bv.y + pv.y);
    ob.z = f2bf(bf2f(v1.z) + bf2f(v2.z) + bv.z + pv.z);
    ob.w = f2bf(bf2f(v1.w) + bf2f(v2.w) + bv.w + pv.w);
    *reinterpret_cast<ushort4*>(outb + base) = ob;
}

// ---------------- combine + add + layernorm: out = LN(p1+p2+bias + res) ----------------
__global__ __launch_bounds__(256) void add_ln2(
    const u16* __restrict__ p1, const u16* __restrict__ p2,
    const float* __restrict__ bias, const u16* __restrict__ res,
    const float* __restrict__ g, const float* __restrict__ be,
    u16* __restrict__ outb, float* __restrict__ outf)
{
    int row = blockIdx.x, tid = threadIdx.x;
    int c0 = tid << 2;
    size_t base = (size_t)row * D_ + c0;
    ushort4 v1 = *reinterpret_cast<const ushort4*>(p1 + base);
    ushort4 v2 = *reinterpret_cast<const ushort4*>(p2 + base);
    float4 bv = *reinterpret_cast<const float4*>(bias + c0);
    ushort4 vr = *reinterpret_cast<const ushort4*>(res + base);
    float vals[4] = { bf2f(v1.x) + bf2f(v2.x) + bv.x + bf2f(vr.x),
                      bf2f(v1.y) + bf2f(v2.y) + bv.y + bf2f(vr.y),
                      bf2f(v1.z) + bf2f(v2.z) + bv.z + bf2f(vr.z),
                      bf2f(v1.w) + bf2f(v2.w) + bv.w + bf2f(vr.w) };
    float s = vals[0] + vals[1] + vals[2] + vals[3];
    __shared__ float red[8];
    #pragma unroll
    for (int off = 32; off; off >>= 1) s += __shfl_xor(s, off);
    int wave = tid >> 6, lane = tid & 63;
    if (lane == 0) red[wave] = s;
    __syncthreads();
    float mean = (red[0] + red[1] + red[2] + red[3]) * (1.0f / D_);
    float vv = 0.0f;
    #pragma unroll
    for (int t = 0; t < 4; ++t) {
        float d = vals[t] - mean;
        vv += d * d;
    }
    #pragma unroll
    for (int off = 32; off; off >>= 1) vv += __shfl_xor(vv, off);
    if (lane == 0) red[4 + wave] = vv;
    __syncthreads();
    float var = (red[4] + red[5] + red[6] + red[7]) * (1.0f / D_);
    float rstd = rsqrtf(var + 1e-5f);
    float4 gv  = *reinterpret_cast<const float4*>(g  + c0);
    float4 bev = *reinterpret_cast<const float4*>(be + c0);
    float o0 = (vals[0] - mean) * rstd * gv.x + bev.x;
    float o1 = (vals[1] - mean) * rstd * gv.y + bev.y;
    float o2 = (vals[2] - mean) * rstd * gv.z + bev.z;
    float o3 = (vals[3] - mean) * rstd * gv.w + bev.w;
    ushort4 ob;
    ob.x = f2bf(o0); ob.y = f2bf(o1); ob.z = f2bf(o2); ob.w = f2bf(o3);
    *reinterpret_cast<ushort4*>(outb + base) = ob;
    if (outf) {
        float4 of = { o0, o1, o2, o3 };
        *reinterpret_cast<float4*>(outf + base) = of;
    }
}

// ---------------- small bf16 GEMM (M=128 heads), BM=64, 16x16 MFMA ----------------
template<int BM>
__global__ __launch_bounds__(256) void gemm_bf16_t(
    const u16* __restrict__ A, int lda, const u16* __restrict__ Wt,
    const float* __restrict__ bias, float* __restrict__ Cf,
    u16* __restrict__ Cb, int ldcb, u16* __restrict__ Cb2, int ldcb2,
    int N, int K, int act)
{
    constexpr int MR   = BM / 32;
    constexpr int AL   = BM / 64;
    constexpr int ABUF = BM * 32;
    __shared__ u16 As[2 * ABUF];
    __shared__ u16 Bs[2 * 4096];
    const int tid  = threadIdx.x;
    const int lane = tid & 63;
    const int wid  = tid >> 6;
    const int wr   = wid >> 1, wc = wid & 1;

    const int rowBase = blockIdx.y * BM;
    const int colBase = blockIdx.x * 128;

    const int fr = lane & 15;
    const int hi = lane >> 4;

    const int sRowL  = lane >> 2;
    const int sChunk = lane & 3;
    const int aRow0 = wid * (BM / 4) + sRowL;
    const int aKey  = (aRow0 >> 1) & 3;
    const u16* aS0 = A + (size_t)(rowBase + aRow0) * lda + ((sChunk ^ aKey) << 3);
    const u16* aS1 = aS0 + (size_t)16 * lda;
    const int ldsA0 = (wid * (BM / 4)) * 32;
    const int ldsA1 = ldsA0 + 512;
    const int bRow0 = wid * 32 + sRowL;
    const int bKey  = (bRow0 >> 1) & 3;
    const u16* bS0 = Wt + (size_t)(colBase + bRow0) * K + ((sChunk ^ bKey) << 3);
    const u16* bS1 = bS0 + (size_t)16 * K;
    const int ldsB0 = (wid * 32) * 32;
    const int ldsB1 = ldsB0 + 512;

    const int swz = ((hi ^ ((fr >> 1) & 3)) << 3);
    const int aRd = (wr * (BM / 2) + fr) * 32 + swz;
    const int bRd = (wc * 64 + fr) * 32 + swz;

    f32x4 acc[MR][4] = {};
    const int nk = K >> 5;

    auto STAGE = [&](int kb, int buf) {
        u16* dA = As + buf * ABUF;
        u16* dB = Bs + buf * 4096;
        gload16(aS0 + kb, dA + ldsA0);
        if constexpr (AL == 2) gload16(aS1 + kb, dA + ldsA1);
        gload16(bS0 + kb, dB + ldsB0);
        gload16(bS1 + kb, dB + ldsB1);
    };

    STAGE(0, 0);
    __builtin_amdgcn_sched_barrier(0);
    STAGE(32, 1);
    __builtin_amdgcn_sched_barrier(0);
    if constexpr (BM == 128) asm volatile("s_waitcnt vmcnt(4)\n\ts_barrier" ::: "memory");
    else                     asm volatile("s_waitcnt vmcnt(3)\n\ts_barrier" ::: "memory");
    __builtin_amdgcn_sched_barrier(0);

    for (int t = 0; t < nk; ++t) {
        const int cur = t & 1;
        const u16* bA = As + cur * ABUF;
        const u16* bB = Bs + cur * 4096;
        bf8_t af[MR], bf[4];
        #pragma unroll
        for (int m = 0; m < MR; ++m)
            af[m] = *reinterpret_cast<const bf8_t*>(&bA[aRd + m * 512]);
        #pragma unroll
        for (int n = 0; n < 4; ++n)
            bf[n] = *reinterpret_cast<const bf8_t*>(&bB[bRd + n * 512]);
        #pragma unroll
        for (int m = 0; m < MR; ++m)
            #pragma unroll
            for (int n = 0; n < 4; ++n)
                acc[m][n] = __builtin_amdgcn_mfma_f32_16x16x32_bf16(af[m], bf[n], acc[m][n], 0, 0, 0);
        if (t == nk - 1) break;
        __builtin_amdgcn_sched_barrier(0);
        asm volatile("s_waitcnt lgkmcnt(0)\n\ts_barrier" ::: "memory");
        __builtin_amdgcn_sched_barrier(0);
        if (t + 2 < nk) {
            STAGE((t + 2) << 5, cur);
            __builtin_amdgcn_sched_barrier(0);
            if constexpr (BM == 128) asm volatile("s_waitcnt vmcnt(4)\n\ts_barrier" ::: "memory");
            else                     asm volatile("s_waitcnt vmcnt(3)\n\ts_barrier" ::: "memory");
        } else {
            asm volatile("s_waitcnt vmcnt(0)\n\ts_barrier" ::: "memory");
        }
        __builtin_amdgcn_sched_barrier(0);
    }

    const int orow = hi << 2;
    #pragma unroll
    for (int m = 0; m < MR; ++m) {
        int r0 = rowBase + wr * (BM / 2) + m * 16 + orow;
        #pragma unroll
        for (int n = 0; n < 4; ++n) {
            int c = colBase + wc * 64 + n * 16 + fr;
            float bv = bias ? bias[c] : 0.0f;
            #pragma unroll
            for (int r = 0; r < 4; ++r) {
                float v = acc[m][n][r] + bv;
                if (act == 1) v = gelu_exact(v);
                if (Cf)  Cf [(size_t)(r0 + r) * N + c] = v;
                if (Cb)  Cb [(size_t)(r0 + r) * ldcb  + c] = f2bf(v);
                if (Cb2) Cb2[(size_t)(r0 + r) * ldcb2 + c] = f2bf(v);
            }
        }
    }
}

// ---------------- logits GEMM: fp32 W streamed, reg-staged pipeline ----------------
__global__ __launch_bounds__(256) void gemm_logits(
    const float* __restrict__ A, int lda, const float* __restrict__ W,
    const float* __restrict__ bias, float* __restrict__ C, int N, int K)
{
    __shared__ u16 As[2][128][40];
    __shared__ u16 Bs[2][128][40];
    const int tid  = threadIdx.x;
    const int lane = tid & 63;
    const int wid  = tid >> 6;
    const int wr   = wid >> 1, wc = wid & 1;
    const int colBase = blockIdx.x * 128;

    const int a_r = tid >> 1;
    const int a_h = (tid & 1) << 4;
    const int b_c = tid & 127;
    const int b_h = (tid >> 7) << 4;

    const int fr = lane & 15;
    const int fk = (lane >> 4) << 3;

    f32x4 acc[4][4] = {};
    const int nvalid = N - colBase;
    const bool valid = b_c < nvalid;
    const int nk = K >> 5;

    float4 aR[4];
    float  bR[16];

    auto LD = [&](int kb) {
        const float* Ap = A + (size_t)a_r * lda + kb + a_h;
        #pragma unroll
        for (int q = 0; q < 4; ++q)
            aR[q] = *reinterpret_cast<const float4*>(Ap + q * 4);
        const float* Wp = W + (size_t)(kb + b_h) * N + colBase + b_c;
        #pragma unroll
        for (int kk = 0; kk < 16; ++kk)
            bR[kk] = valid ? Wp[(size_t)kk * N] : 0.0f;
    };
    auto ST = [&](int buf) {
        #pragma unroll
        for (int q = 0; q < 4; ++q) {
            ushort4 bb;
            bb.x = f2bf(aR[q].x); bb.y = f2bf(aR[q].y);
            bb.z = f2bf(aR[q].z); bb.w = f2bf(aR[q].w);
            *reinterpret_cast<ushort4*>(&As[buf][a_r][a_h + q * 4]) = bb;
        }
        u16 tmp[16];
        #pragma unroll
        for (int kk = 0; kk < 16; ++kk) tmp[kk] = f2bf(bR[kk]);
        *reinterpret_cast<bf8_t*>(&Bs[buf][b_c][b_h])     = *reinterpret_cast<const bf8_t*>(tmp);
        *reinterpret_cast<bf8_t*>(&Bs[buf][b_c][b_h + 8]) = *reinterpret_cast<const bf8_t*>(tmp + 8);
    };

    LD(0); ST(0);
    __syncthreads();

    for (int t = 0; t < nk; ++t) {
        if (t + 1 < nk) LD((t + 1) << 5);
        const int cur = t & 1;
        bf8_t af[4], bfv[4];
        #pragma unroll
        for (int m = 0; m < 4; ++m)
            af[m] = *reinterpret_cast<const bf8_t*>(&As[cur][wr * 64 + m * 16 + fr][fk]);
        #pragma unroll
        for (int n = 0; n < 4; ++n)
            bfv[n] = *reinterpret_cast<const bf8_t*>(&Bs[cur][wc * 64 + n * 16 + fr][fk]);
        #pragma unroll
        for (int m = 0; m < 4; ++m)
            #pragma unroll
            for (int n = 0; n < 4; ++n)
                acc[m][n] = __builtin_amdgcn_mfma_f32_16x16x32_bf16(af[m], bfv[n], acc[m][n], 0, 0, 0);
        if (t + 1 < nk) ST(cur ^ 1);
        __syncthreads();
    }

    const int orow = (lane >> 4) << 2;
    #pragma unroll
    for (int m = 0; m < 4; ++m) {
        int r0 = wr * 64 + m * 16 + orow;
        #pragma unroll
        for (int n = 0; n < 4; ++n) {
            int c = colBase + wc * 64 + n * 16 + fr;
            if (c < N) {
                float bv = bias ? bias[c] : 0.0f;
                #pragma unroll
                for (int r = 0; r < 4; ++r)
                    C[(size_t)(r0 + r) * N + c] = acc[m][n][r] + bv;
            }
        }
    }
}

// ---------------- self-attention (per (b,h) block) ----------------
__global__ __launch_bounds__(256) void attn_kernel(
    const u16* __restrict__ qkv, const float* __restrict__ rt, const int* __restrict__ rm,
    u16* __restrict__ ctxb)
{
    int bh = blockIdx.x;
    int b = bh >> 4, h = bh & 15;
    __shared__ float qs[S_][DK_ + 1], ks[S_][DK_ + 1], vs[S_][DK_ + 1];
    __shared__ float rts[5][DK_];
    __shared__ float Rs[S_][8];
    int tid = threadIdx.x;
    int wave = tid >> 6, lane = tid & 63;

    for (int idx = tid; idx < S_ * DK_; idx += 256) {
        int s = idx >> 6, d = idx & 63;
        size_t g = ((size_t)(b * S_ + s)) * (3 * D_) + h * DK_ + d;
        qs[s][d] = bf2f(qkv[g]);
        ks[s][d] = bf2f(qkv[g + D_]);
        vs[s][d] = bf2f(qkv[g + 2 * D_]);
    }
    for (int i = tid; i < 5 * DK_; i += 256)
        rts[i >> 6][i & 63] = rt[i];
    __syncthreads();

    for (int t = tid; t < S_ * 5; t += 256) {
        int i = t / 5, r = t - 5 * i;
        float a = 0.0f;
        #pragma unroll 8
        for (int d = 0; d < DK_; ++d) a += qs[i][d] * rts[r][d];
        Rs[i][r] = a;
    }
    __syncthreads();

    const float scale = 0.125f;
    for (int i = wave; i < S_; i += 4) {
        float sc = -INFINITY;
        if (lane < S_) {
            float acc = 0.0f;
            #pragma unroll 8
            for (int d = 0; d < DK_; ++d) acc += qs[i][d] * ks[lane][d];
            sc = acc * scale + 0.5f * Rs[i][rm[i * S_ + lane]];
        }
        float m = sc;
        #pragma unroll
        for (int off = 32; off; off >>= 1) m = fmaxf(m, __shfl_xor(m, off));
        float e = (lane < S_) ? expf(sc - m) : 0.0f;
        float sum = e;
        #pragma unroll
        for (int off = 32; off; off >>= 1) sum += __shfl_xor(sum, off);
        float aval = e / sum;

        float acc = 0.0f;
        for (int j = 0; j < S_; ++j) {
            float aj = __shfl(aval, j);
            acc += aj * vs[j][lane];
        }
        ctxb[((size_t)(b * S_ + i)) * D_ + h * DK_ + lane] = f2bf(acc);
    }
}

// ---------------- user embedding gather ----------------
__global__ __launch_bounds__(256) void gather_user(
    const float* __restrict__ ut, const int* __restrict__ ids,
    u16* __restrict__ o1, int ld1, u16* __restrict__ o2, int ld2)
{
    int b = blockIdx.x;
    int uid = ids[b];
    for (int d = threadIdx.x; d < D_; d += 256) {
        u16 v = f2bf(ut[(size_t)uid * D_ + d]);
        o1[(size_t)b * ld1 + d] = v;
        o2[(size_t)b * ld2 + d] = v;
    }
}

// ---------------- cross attention (q_len = 1); K/V merged [BS][2048] ----------------
__global__ __launch_bounds__(64) void cross_attn(
    const u16* __restrict__ qh, const u16* __restrict__ kv, u16* __restrict__ up)
{
    int bh = blockIdx.x;
    int b = bh >> 4, h = bh & 15;
    int lane = threadIdx.x;
    __shared__ float qv[DK_];
    qv[lane] = bf2f(qh[(size_t)b * D_ + h * DK_ + lane]);
    __syncthreads();
    float sc = -INFINITY;
    if (lane < S_) {
        float acc = 0.0f;
        const u16* krow = kv + ((size_t)(b * S_ + lane)) * 2048 + h * DK_;
        #pragma unroll 8
        for (int d = 0; d < DK_; ++d) acc += qv[d] * bf2f(krow[d]);
        sc = acc * 0.125f;
    }
    float m = sc;
    #pragma unroll
    for (int off = 32; off; off >>= 1) m = fmaxf(m, __shfl_xor(m, off));
    float e = (lane < S_) ? expf(sc - m) : 0.0f;
    float sum = e;
    #pragma unroll
    for (int off = 32; off; off >>= 1) sum += __shfl_xor(sum, off);
    float aval = e / sum;
    float acc = 0.0f;
    for (int j = 0; j < S_; ++j) {
        float aj = __shfl(aval, j);
        acc += aj * bf2f(kv[((size_t)(b * S_ + j)) * 2048 + 1024 + h * DK_ + lane]);
    }
    up[(size_t)b * D_ + h * DK_ + lane] = f2bf(acc);
}

// ---------------- sequence mean ----------------
__global__ __launch_bounds__(256) void seq_mean(
    const float* __restrict__ x,
    u16* __restrict__ o1, int ld1, u16* __restrict__ o2, int ld2)
{
    int b = blockIdx.x;
    for (int d = threadIdx.x; d < D_; d += 256) {
        float s = 0.0f;
        for (int si = 0; si < S_; ++si)
            s += x[((size_t)(b * S_ + si)) * D_ + d];
        u16 v = f2bf(s * (1.0f / S_));
        o1[(size_t)b * ld1 + d] = v;
        o2[(size_t)b * ld2 + d] = v;
    }
}

// ---------------- fused final heads ----------------
__global__ __launch_bounds__(256) void heads_final(
    const float* __restrict__ h1cn, const float* __restrict__ h1r, const float* __restrict__ ho,
    const float* __restrict__ c_w2, const float* __restrict__ c_b2,
    const float* __restrict__ r_w2, const float* __restrict__ r_b2,
    const float* __restrict__ o_w2, const float* __restrict__ o_b2,
    float* __restrict__ comp, float* __restrict__ rating, float* __restrict__ order)
{
    int b = blockIdx.x;
    int lane = threadIdx.x & 63, wv = threadIdx.x >> 6;
    if (wv == 0) {
        float s = 0.0f;
        for (int d = lane; d < D_; d += 64) s += h1cn[(size_t)b * 2048 + d] * c_w2[d];
        #pragma unroll
        for (int off = 32; off; off >>= 1) s += __shfl_xor(s, off);
        if (lane == 0) comp[b] = 1.0f / (1.0f + expf(-(s + c_b2[0])));
    } else if (wv == 1) {
        float s = 0.0f;
        for (int d = lane; d < D_; d += 64) s += h1r[(size_t)b * D_ + d] * r_w2[d];
        #pragma unroll
        for (int off = 32; off; off >>= 1) s += __shfl_xor(s, off);
        if (lane == 0) rating[b] = s + r_b2[0];
    } else if (wv == 2) {
        float s0 = 0.0f, s1 = 0.0f;
        for (int d = lane; d < 512; d += 64) {
            float hv = ho[(size_t)b * 512 + d];
            s0 += hv * o_w2[d * 2];
            s1 += hv * o_w2[d * 2 + 1];
        }
        #pragma unroll
        for (int off = 32; off; off >>= 1) { s0 += __shfl_xor(s0, off); s1 += __shfl_xor(s1, off); }
        if (lane == 0) {
            float a = s0 + o_b2[0], c = s1 + o_b2[1];
            float m = fmaxf(a, c);
            float ea = expf(a - m), ec = expf(c - m);
            float s = ea + ec;
            order[b * 2] = ea / s;
            order[b * 2 + 1] = ec / s;
        }
    }
}

// ---------------- host-side launcher ----------------
extern "C" void kernel_launch(void* const* d_in, const int* in_sizes, int n_in,
                              void* d_out, int out_size, void* d_ws, size_t ws_size,
                              hipStream_t stream) {
    const float* movie_table = (const float*)d_in[0];
    const float* fran_table  = (const float*)d_in[1];
    const float* entry_table = (const float*)d_in[2];
    const float* proj_w      = (const float*)d_in[3];
    const float* proj_b      = (const float*)d_in[4];
    const float* wq          = (const float*)d_in[5];
    const float* bq          = (const float*)d_in[6];
    const float* wk          = (const float*)d_in[7];
    const float* bk          = (const float*)d_in[8];
    const float* wv          = (const float*)d_in[9];
    const float* bv          = (const float*)d_in[10];
    const float* wo          = (const float*)d_in[11];
    const float* bo          = (const float*)d_in[12];
    const float* rel_table   = (const float*)d_in[13];
    const float* aln_g       = (const float*)d_in[14];
    const float* aln_b       = (const float*)d_in[15];
    const float* f_w1        = (const float*)d_in[16];
    const float* f_b1        = (const float*)d_in[17];
    const float* f_w2        = (const float*)d_in[18];
    const float* f_b2        = (const float*)d_in[19];
    const float* ln_g        = (const float*)d_in[20];
    const float* ln_b        = (const float*)d_in[21];
    const float* user_table  = (const float*)d_in[22];
    const float* mq_w        = (const float*)d_in[23];
    const float* mq_b        = (const float*)d_in[24];
    const float* mk_w        = (const float*)d_in[25];
    const float* mk_b        = (const float*)d_in[26];
    const float* mv_w        = (const float*)d_in[27];
    const float* mv_b        = (const float*)d_in[28];
    const float* mo_w        = (const float*)d_in[29];
    const float* mo_b        = (const float*)d_in[30];
    const float* c_w1        = (const float*)d_in[31];
    const float* c_b1        = (const float*)d_in[32];
    const float* c_w2        = (const float*)d_in[33];
    const float* c_b2        = (const float*)d_in[34];
    const float* n_w1        = (const float*)d_in[35];
    const float* n_b1        = (const float*)d_in[36];
    const float* n_w2        = (const float*)d_in[37];
    const float* n_b2        = (const float*)d_in[38];
    const float* r_w1        = (const float*)d_in[39];
    const float* r_b1        = (const float*)d_in[40];
    const float* r_w2        = (const float*)d_in[41];
    const float* r_b2        = (const float*)d_in[42];
    const float* o_w1        = (const float*)d_in[43];
    const float* o_b1        = (const float*)d_in[44];
    const float* o_w2        = (const float*)d_in[45];
    const float* o_b2        = (const float*)d_in[46];
    const int* user_ids      = (const int*)d_in[47];
    const int* movie_ids     = (const int*)d_in[48];
    const int* franchise_ids = (const int*)d_in[49];
    const int* entry_types   = (const int*)d_in[50];
    const int* relation_mat  = (const int*)d_in[51];

    // ---- workspace layout (u16 units) ----
    u16* up16 = (u16*)d_ws;
    u16* proj_wt = up16;                                   // [1024][1536]
    u16* wqkv_t  = proj_wt + (size_t)1024 * 1536;          // [4][3072][1024]
    u16* wo_t    = wqkv_t  + (size_t)4 * 3072 * 1024;      // [4][1024][1024]
    u16* fw1_buf = wo_t    + (size_t)4 * 1024 * 1024;      // [4096][1024]
    u16* fw2_buf = fw1_buf + (size_t)4096 * 1024;          // [1024][4096]
    u16* mq_t    = fw2_buf + (size_t)1024 * 4096;          // [1024][1024]
    u16* mk_t    = mq_t    + (size_t)1024 * 1024;          // mk|mv = [2048][1024]
    u16* mv_t    = mk_t    + (size_t)1024 * 1024;
    u16* mo_t    = mv_t    + (size_t)1024 * 1024;
    u16* cn_w1t  = mo_t    + (size_t)1024 * 1024;          // [2048][2048]
    u16* r_w1t   = cn_w1t  + (size_t)2048 * 2048;          // [1024][3072]
    u16* o_w1t   = r_w1t   + (size_t)1024 * 3072;          // [512][1024]
    u16* ffb     = o_w1t   + (size_t)512 * 1024;           // [6400][4096]
    u16* xinb    = ffb;                                    // [6400][1536] (dead after proj)
    u16* xb      = ffb     + (size_t)BS_ * FF_;            // [6400][1024]
    u16* xb2     = xb      + (size_t)BS_ * D_;             // [6400][1024]
    u16* qkvb    = xb2     + (size_t)BS_ * D_;             // [6400][3072]
    u16* kvb     = qkvb    + (size_t)BS_ * 3 * D_;         // [6400][2048]
    u16* ctxb    = kvb;
    u16* ueb     = kvb     + (size_t)BS_ * 2 * D_;         // [128][1024]
    u16* upb_pre = ueb     + (size_t)B_ * D_;              // [128][1024]
    u16* cib     = upb_pre + (size_t)B_ * D_;              // [128][2048]
    u16* rib     = cib     + (size_t)B_ * 2 * D_;          // [128][3072]
    float* fp    = (float*)(rib + (size_t)B_ * 3 * D_);
    float* bqkv  = fp;                                     // [4][3072]
    float* bcn   = bqkv + 4 * 3072;                        // [2048]
    float* bkv   = bcn  + 2048;                            // [2048]
    float* pet   = bkv  + 2048;                            // [50][1024]
    float* h1cn  = pet  + 50 * 1024;                       // [128][2048]
    float* h1r   = h1cn + (size_t)B_ * 2048;               // [128][1024]
    float* ho    = h1r  + (size_t)B_ * D_;                 // [128][512]

    // split-K partial buffers (bf16) aliased over dead regions ([6400][1024] u16 each)
    u16* pQK = qkvb;   // dead after attn / before QKV
    u16* pKV = kvb;    // dead except when ctx/mkmv live
    u16* pFF = ffb;    // dead before FF1 of the layer

    // ---- d_out layout ----
    float* xout    = (float*)d_out;                 // [BS, D]
    float* comp    = xout + (size_t)BS_ * D_;       // [B,1]
    float* logits  = comp + B_;                     // [B,V]
    float* rating  = logits + (size_t)B_ * V_;      // [B,1]
    float* order   = rating + B_;                   // [B,2]
    float* upref   = order + 2 * B_;                // [B,D]

    dim3 blk(256);

    // ---- weight conversion pass ----
    wtrans<<<dim3(32, 48, 1), blk, 0, stream>>>(proj_w, proj_wt, 1536, 1024, 0, 0, 0);
    wtrans_qkv<<<dim3(32, 32, 12), blk, 0, stream>>>(wq, wk, wv, wqkv_t);
    WT8 w8;
    w8.s[0] = wo;                 w8.d[0] = wo_t;
    w8.s[1] = wo + 1048576;       w8.d[1] = wo_t + 1048576;
    w8.s[2] = wo + 2097152;       w8.d[2] = wo_t + 2097152;
    w8.s[3] = wo + 3145728;       w8.d[3] = wo_t + 3145728;
    w8.s[4] = mq_w;               w8.d[4] = mq_t;
    w8.s[5] = mk_w;               w8.d[5] = mk_t;
    w8.s[6] = mv_w;               w8.d[6] = mv_t;
    w8.s[7] = mo_w;               w8.d[7] = mo_t;
    wtrans8<<<dim3(32, 32, 8), blk, 0, stream>>>(w8);
    wtrans<<<dim3(32, 64, 1), blk, 0, stream>>>(c_w1, cn_w1t, 2048, 1024, 0, 0, 0);
    wtrans<<<dim3(32, 64, 1), blk, 0, stream>>>(n_w1, cn_w1t, 2048, 1024, 0, 0, 1024);
    wtrans<<<dim3(32, 96, 1), blk, 0, stream>>>(r_w1, r_w1t, 3072, 1024, 0, 0, 0);
    wtrans<<<dim3(16, 32, 1), blk, 0, stream>>>(o_w1, o_w1t, 1024, 512, 0, 0, 0);
    setup_misc<<<dim3(56), blk, 0, stream>>>(bq, bk, bv, c_b1, n_b1, mk_b, mv_b,
                                             bqkv, bcn, bkv, pet);

    // ---- encoder input: proj split-K (bf16 partials over qkvb/kvb) + combine ----
    embed_concat<<<BS_, blk, 0, stream>>>(movie_table, fran_table, entry_table,
                                          movie_ids, franchise_ids, entry_types, xinb);
    gemm_sk32<<<dim3(8, 50, 2), blk, 0, stream>>>(xinb, 1536, proj_wt, 1536,
                                                  pQK, pKV, D_, 768);
    combine_bias_pe<<<BS_, blk, 0, stream>>>(pQK, pKV, proj_b, pet, xb);

    // ---- transformer layers (x ping-pong: xb -> xb2 -> xb) ----
    for (int l = 0; l < L_; ++l) {
        gemm128_w32<<<dim3(24, 50), blk, 0, stream>>>(xb, 1024,
                wqkv_t + (size_t)l * 3145728, bqkv + l * 3072,
                qkvb, 3072, 3 * D_, D_, 0);
        attn_kernel<<<B_ * H_, blk, 0, stream>>>(qkvb, rel_table + (size_t)l * 5 * DK_,
                                                 relation_mat, ctxb);
        // WO split-K: partials over qkvb (dead) + ffb (dead until FF1)
        gemm_sk32<<<dim3(8, 50, 2), blk, 0, stream>>>(ctxb, 1024,
                wo_t + (size_t)l * 1048576, 1024, pQK, pFF, D_, 512);
        add_ln2<<<BS_, blk, 0, stream>>>(pQK, pFF, bo + l * D_, xb,
                                         aln_g + l * D_, aln_b + l * D_, xb2, nullptr);
        wtrans_ff<<<dim3(128, 32, 2), blk, 0, stream>>>(f_w1 + (size_t)l * D_ * FF_,
                                                        f_w2 + (size_t)l * FF_ * D_,
                                                        fw1_buf, fw2_buf);
        gemm128_w32<<<dim3(32, 50), blk, 0, stream>>>(xb2, 1024, fw1_buf, f_b1 + l * FF_,
                ffb, 4096, FF_, D_, 1);
        // FF2 split-K: partials over qkvb + kvb (both dead here)
        gemm_sk32<<<dim3(8, 50, 2), blk, 0, stream>>>(ffb, 4096, fw2_buf, 4096,
                                                      pQK, pKV, D_, 2048);
        add_ln2<<<BS_, blk, 0, stream>>>(pQK, pKV, f_b2 + l * D_, xb2,
                                         ln_g + l * D_, ln_b + l * D_, xb,
                                         (l == L_ - 1) ? xout : nullptr);
    }

    // ---- user cross-attention ----
    gather_user<<<B_, blk, 0, stream>>>(user_table, user_ids, ueb, 1024, rib, 3072);
    gemm_bf16_t<64><<<dim3(8, 2), blk, 0, stream>>>(ueb, 1024, mq_t, mq_b,
            nullptr, qkvb, 1024, nullptr, 0, D_, D_, 0);
    gemm128_w32<<<dim3(16, 50), blk, 0, stream>>>(xb, 1024, mk_t, bkv,
            kvb, 2048, 2 * D_, D_, 0);
    cross_attn<<<B_ * H_, dim3(64), 0, stream>>>(qkvb, kvb, upb_pre);
    gemm_bf16_t<64><<<dim3(8, 2), blk, 0, stream>>>(upb_pre, 1024, mo_t, mo_b,
            upref, cib, 2048, rib + 1024, 3072, D_, D_, 0);

    // ---- sequence mean (writes into both concats) ----
    seq_mean<<<B_, blk, 0, stream>>>(xout, cib + 1024, 2048, rib + 2048, 3072);

    // ---- heads ----
    gemm_bf16_t<64><<<dim3(16, 2), blk, 0, stream>>>(cib, 2048, cn_w1t, bcn,
            h1cn, nullptr, 0, nullptr, 0, 2048, 2048, 1);
    gemm_bf16_t<64><<<dim3(8, 2), blk, 0, stream>>>(rib, 3072, r_w1t, r_b1,
            h1r, nullptr, 0, nullptr, 0, D_, 3072, 1);
    gemm_bf16_t<64><<<dim3(4, 2), blk, 0, stream>>>(cib, 2048, o_w1t, o_b1,
            ho, nullptr, 0, nullptr, 0, 512, D_, 1);
    gemm_logits<<<dim3(782, 1), blk, 0, stream>>>(h1cn + 1024, 2048, n_w2, n_b2,
                                                  logits, V_, D_);
    heads_final<<<B_, blk, 0, stream>>>(h1cn, h1r, ho, c_w2, c_b2, r_w2, r_b2,
                                        o_w2, o_b2, comp, rating, order);
}